// Round 10
// baseline (1726.027 us; speedup 1.0000x reference)
//
#include <hip/hip_runtime.h>
#include <math.h>

#define BATCH 16
#define NPTS  4096
#define NCTR  512
#define STEM  128
#define TOK   256
#define D_IN  155   // 128 + 3 + 24
#define D_TOK 992   // 128 + 3*256 + 96

typedef short s16x8 __attribute__((ext_vector_type(8)));
typedef float f32x4 __attribute__((ext_vector_type(4)));

// 10000^(-i/15), i=0..15 (token-PE frequencies)
static constexpr float FR15c[16] = {
    1.0f, 0.5411695265464638f, 0.2928644487857941f, 0.15848931670188904f,
    0.08576958626508713f, 0.04641588851809502f, 0.02511886507272720f, 0.01359356392547488f,
    0.007356422487646341f, 0.003981071710586548f, 0.002154434798285365f, 0.001165914465673268f,
    0.0006309573450125754f, 0.0003414548910222948f, 0.0001847849769866168f, 0.0001f};

__device__ __forceinline__ unsigned short f2bf(float f) {
    unsigned u = __float_as_uint(f);
    u += 0x7FFF + ((u >> 16) & 1);
    return (unsigned short)(u >> 16);
}
__device__ __forceinline__ float bf2f(unsigned short b) {
    return __uint_as_float(((unsigned)b) << 16);
}

// split 8 f32 -> hi/lo bf16 fragments via v_cvt_pk_bf16_f32 (RNE)
__device__ __forceinline__ void bsplit8(const float* v, s16x8& hi, s16x8& lo) {
    union { s16x8 s; unsigned w[4]; } H, L;
#pragma unroll
    for (int p = 0; p < 4; ++p) {
        unsigned hp, lp;
        asm("v_cvt_pk_bf16_f32 %0, %1, %2" : "=v"(hp) : "v"(v[2 * p]), "v"(v[2 * p + 1]));
        float r0 = v[2 * p]     - __uint_as_float(hp << 16);
        float r1 = v[2 * p + 1] - __uint_as_float(hp & 0xffff0000u);
        asm("v_cvt_pk_bf16_f32 %0, %1, %2" : "=v"(lp) : "v"(r0), "v"(r1));
        H.w[p] = hp; L.w[p] = lp;
    }
    hi = H.s; lo = L.s;
}

// pack two f32 into two (hi16|lo16) u32 words
__device__ __forceinline__ void pkpair(float v0, float v1, unsigned& w0, unsigned& w1) {
    unsigned hp, lp;
    asm("v_cvt_pk_bf16_f32 %0, %1, %2" : "=v"(hp) : "v"(v0), "v"(v1));
    float r0 = v0 - __uint_as_float(hp << 16);
    float r1 = v1 - __uint_as_float(hp & 0xffff0000u);
    asm("v_cvt_pk_bf16_f32 %0, %1, %2" : "=v"(lp) : "v"(r0), "v"(r1));
    w0 = (hp << 16) | (lp & 0xffffu);
    w1 = (hp & 0xffff0000u) | (lp >> 16);
}

// B-fragment direct load: global (L2-hot) -> VGPR, 16B hi + 16B lo per lane
__device__ __forceinline__ void loadB(const unsigned short* __restrict__ pk,
                                      int frag, int l, s16x8& bh, s16x8& bl) {
    const unsigned short* p = pk + (size_t)frag * 1024 + (size_t)l * 8;
    bh = *(const s16x8*)p;
    bl = *(const s16x8*)(p + 512);
}

// fast exact-GELU: A&S 7.1.26 erf (|abs err| < 2e-7)
__device__ __forceinline__ float gelu_exact(float x) {
    float z = x * 0.70710678118654752f;
    float a = fabsf(z);
    float t = __builtin_amdgcn_rcpf(fmaf(0.3275911f, a, 1.0f));
    float p = fmaf(1.061405429f, t, -1.453152027f);
    p = fmaf(p, t, 1.421413741f);
    p = fmaf(p, t, -0.284496736f);
    p = fmaf(p, t, 0.254829592f);
    p = p * t;
    float e = __expf(-z * z);
    float y = fmaf(-p, e, 1.0f);
    y = (z < 0.0f) ? -y : y;
    return 0.5f * x * (1.0f + y);
}

// exact, non-contracted squared distance to match numpy f32 rounding
__device__ __forceinline__ float sq3(float ax, float ay, float az,
                                     float bx, float by, float bz) {
    float dx = __fsub_rn(ax, bx);
    float dy = __fsub_rn(ay, by);
    float dz = __fsub_rn(az, bz);
    float d = __fmul_rn(dx, dx);
    d = __fadd_rn(d, __fmul_rn(dy, dy));
    d = __fadd_rn(d, __fmul_rn(dz, dz));
    return d;
}

// ---------------- FPS: 1024 threads, LDS-resident, 1 barrier/step ----------
// 16 waves = 4 waves/SIMD hide latencies (256-thread version ran at 1
// wave/SIMD, fully latency-exposed, ~2750 cy/step). Combine across 16 wave
// partials via 16-lane shfl butterfly; total order on (val, idx) keeps FPS
// indices bit-identical to the reference argmax.
__global__ __launch_bounds__(1024) void fps_kernel(const float* __restrict__ xyz,
                                                   int* __restrict__ center_idx,
                                                   float* __restrict__ pc_ws,
                                                   float* __restrict__ pc_out) {
    int b = blockIdx.x;
    int t = threadIdx.x;
    const int w = t >> 6, lane = t & 63;
    const float* X = xyz + (size_t)b * NPTS * 3;
    __shared__ __align__(16) float sxyz[NPTS * 3];  // 48 KB
    __shared__ float swv[2][16];
    __shared__ int   swi[2][16];
    __shared__ int   hist[NCTR];                    // 2 KB
    {
        const float4* src = (const float4*)X;
        float4* dst = (float4*)sxyz;
        for (int i = t; i < NPTS * 3 / 4; i += 1024) dst[i] = src[i];
    }
    __syncthreads();
    float px[4], py[4], pz[4], dist[4];
#pragma unroll
    for (int j = 0; j < 4; ++j) {
        int i = t + 1024 * j;
        px[j] = sxyz[i * 3 + 0];
        py[j] = sxyz[i * 3 + 1];
        pz[j] = sxyz[i * 3 + 2];
        dist[j] = 1e10f;
    }
    int far = 0;
    for (int s = 0; s < NCTR; ++s) {
        if (t == 0) hist[s] = far;
        float cx = sxyz[far * 3 + 0];
        float cy = sxyz[far * 3 + 1];
        float cz = sxyz[far * 3 + 2];
        float bv = -1.0f;
        int bi = 0;
#pragma unroll
        for (int j = 0; j < 4; ++j) {
            float d = sq3(px[j], py[j], pz[j], cx, cy, cz);
            float nd = fminf(dist[j], d);
            dist[j] = nd;
            if (nd > bv) { bv = nd; bi = t + 1024 * j; }  // strict >: earliest idx
        }
#pragma unroll
        for (int off = 32; off >= 1; off >>= 1) {
            float ov = __shfl_xor(bv, off, 64);
            int   oi = __shfl_xor(bi, off, 64);
            if (ov > bv || (ov == bv && oi < bi)) { bv = ov; bi = oi; }
        }
        const int p = s & 1;
        if (lane == 0) { swv[p][w] = bv; swi[p][w] = bi; }
        __syncthreads();
        // combine 16 wave partials: butterfly within each 16-lane group
        bv = swv[p][lane & 15];
        bi = swi[p][lane & 15];
#pragma unroll
        for (int m = 1; m <= 8; m <<= 1) {
            float ov = __shfl_xor(bv, m, 64);
            int   oi = __shfl_xor(bi, m, 64);
            if (ov > bv || (ov == bv && oi < bi)) { bv = ov; bi = oi; }
        }
        far = bi;
    }
    __syncthreads();
    for (int s = t; s < NCTR; s += 1024) {
        int idx = hist[s];
        center_idx[b * NCTR + s] = idx;
        float cx = sxyz[idx * 3], cy = sxyz[idx * 3 + 1], cz = sxyz[idx * 3 + 2];
        size_t po = (size_t)(b * NCTR + s) * 3;
        pc_ws[po] = cx; pc_ws[po + 1] = cy; pc_ws[po + 2] = cz;
        pc_out[po] = cx; pc_out[po + 1] = cy; pc_out[po + 2] = cz;
    }
}

// ---------------- Ball query (unchanged) ----------------------------------
template <int K>
__global__ __launch_bounds__(256) void ballq_kernel(const float* __restrict__ xyz,
                                                    const float* __restrict__ pc,
                                                    int* __restrict__ nbr,
                                                    float rr) {
    int cid = blockIdx.x * 4 + (threadIdx.x >> 6);
    int lane = threadIdx.x & 63;
    int b = cid >> 9;
    const float* X = xyz + (size_t)b * NPTS * 3;
    float cx = pc[(size_t)cid * 3 + 0];
    float cy = pc[(size_t)cid * 3 + 1];
    float cz = pc[(size_t)cid * 3 + 2];
    int cnt = 0, first = 0;
    bool have_first = false;
    long long base = (long long)cid * K;
    for (int it = 0; it < NPTS / 64; ++it) {
        int i = it * 64 + lane;
        float d = sq3(cx, cy, cz, X[i * 3], X[i * 3 + 1], X[i * 3 + 2]);
        bool ok = d <= rr;
        unsigned long long mask = __ballot(ok);
        if (!have_first && mask) {
            first = it * 64 + (int)__builtin_ctzll(mask);
            have_first = true;
        }
        int pos = cnt + (int)__popcll(mask & ((1ull << lane) - 1ull));
        if (ok && pos < K) nbr[base + pos] = i;
        cnt += (int)__popcll(mask);
        if (cnt >= K) break;
    }
    int fill = cnt < K ? cnt : K;
    for (int j = fill + lane; j < K; j += 64) nbr[base + j] = first;
}

// ---------------- Weight pack: hi-plane/lo-plane bf16 MFMA B-frags --------
__global__ __launch_bounds__(256) void pack_w(const float* __restrict__ Wbase,
                                              unsigned short* __restrict__ out,
                                              int Kdim, int KS) {
    int s = blockIdx.y;
    const float* W = Wbase + (size_t)s * Kdim * TOK;
    unsigned short* o = out + (size_t)s * 16 * KS * 64 * 16;
    int tid = blockIdx.x * 256 + threadIdx.x;
    if (tid >= 16 * KS * 64) return;
    int lane = tid & 63;
    int frag = tid >> 6;
    int ks = frag % KS;
    int ct = frag / KS;
    int col = ct * 16 + (lane & 15);
    int k0 = ks * 32 + (lane >> 4) * 8;
    unsigned short* hi = o + (size_t)frag * 1024 + lane * 8;
    unsigned short* lo = hi + 512;
#pragma unroll
    for (int j = 0; j < 8; ++j) {
        int k = k0 + j;
        float v = (k < Kdim) ? W[(size_t)k * TOK + col] : 0.0f;
        unsigned short h = f2bf(v);
        hi[j] = h;
        lo[j] = f2bf(v - bf2f(h));
    }
}

// ---------------- Per-scale grouped MLP via bf16x3 MFMA --------------------
// 32-row blocks, ONE-PASS skeleton (proven round-6/round-9 structure).
// K=64 centers span two blocks: each block emits a PARTIAL max row to
// sf2p[2*c+half]; token_mfma combines with fmaxf.
template <int K>
__global__ __launch_bounds__(256, 2) void scale_mfma(
    const float* __restrict__ xyz, const float* __restrict__ pf,
    const unsigned short* __restrict__ pk1, const float* __restrict__ b1,
    const float* __restrict__ g1, const float* __restrict__ be1,
    const unsigned short* __restrict__ pk2, const float* __restrict__ b2,
    const float* __restrict__ g2, const float* __restrict__ be2,
    const int* __restrict__ nbr, const float* __restrict__ pc,
    float* __restrict__ outf) {
    __shared__ unsigned int hpk[32][260];   // 33 KB packed-bf16 h (32 rows)
    __shared__ float lnred[4][32][2];       // 1 KB
    const int w = threadIdx.x >> 6, l = threadIdx.x & 63;
    const int lg = l >> 4, li = l & 15;
    const int ws4 = 4 * w;

    int nb[2];
    float relx[2], rely[2], relz[2];
#pragma unroll
    for (int rb = 0; rb < 2; ++rb) {
        int row_g = blockIdx.x * 32 + rb * 16 + li;
        int c = (blockIdx.x * 32 + rb * 16) / K;   // li never crosses a center
        int b = c >> 9;
        int n = nbr[row_g];
        nb[rb] = b * NPTS + n;
        const float* X = xyz + (size_t)nb[rb] * 3;
        const float* C = pc + (size_t)c * 3;
        relx[rb] = __fsub_rn(X[0], C[0]);
        rely[rb] = __fsub_rn(X[1], C[1]);
        relz[rb] = __fsub_rn(X[2], C[2]);
    }

    // ---------------- MLP1: [32 x 160] @ [160 x 64-slice] (bf16x3) --------
    f32x4 acc1[2][4];
#pragma unroll
    for (int rb = 0; rb < 2; ++rb)
#pragma unroll
        for (int ctl = 0; ctl < 4; ++ctl) acc1[rb][ctl] = (f32x4){0.f, 0.f, 0.f, 0.f};

#pragma unroll
    for (int ks = 0; ks < 5; ++ks) {
        s16x8 Bh[4], Bl[4];
#pragma unroll
        for (int ctl = 0; ctl < 4; ++ctl)
            loadB(pk1, (ws4 + ctl) * 5 + ks, l, Bh[ctl], Bl[ctl]);
        s16x8 Ah[2], Al[2];
#pragma unroll
        for (int rb = 0; rb < 2; ++rb) {
            float v[8];
            if (ks < 4) {
                const float* src = pf + (size_t)nb[rb] * STEM + ks * 32 + lg * 8;
                float4 f0 = *(const float4*)src;
                float4 f1 = *(const float4*)(src + 4);
                v[0] = f0.x; v[1] = f0.y; v[2] = f0.z; v[3] = f0.w;
                v[4] = f1.x; v[5] = f1.y; v[6] = f1.z; v[7] = f1.w;
            } else {
#pragma unroll
                for (int j = 0; j < 8; ++j) {
                    int ch = lg * 8 + j;
                    float val = 0.0f;
                    if (ch < 3) {
                        val = (ch == 0) ? relx[rb] : ((ch == 1) ? rely[rb] : relz[rb]);
                    } else if (ch < 27) {
                        int rem = ch - 3;
                        int axis = rem >> 3, r8 = rem & 7;
                        int fi = (r8 < 4) ? r8 : r8 - 4;
                        float fr = (fi == 0) ? 1.0f
                                  : (fi == 1) ? 0.046415888336127795f
                                  : (fi == 2) ? 0.0021544346900318843f : 1e-4f;
                        float rl = (axis == 0) ? relx[rb] : ((axis == 1) ? rely[rb] : relz[rb]);
                        float ang = rl * fr;
                        val = (r8 < 4) ? __sinf(ang) : __cosf(ang);
                    }
                    v[j] = val;
                }
            }
            bsplit8(v, Ah[rb], Al[rb]);
        }
#pragma unroll
        for (int ctl = 0; ctl < 4; ++ctl)
#pragma unroll
            for (int rb = 0; rb < 2; ++rb) {
                acc1[rb][ctl] = __builtin_amdgcn_mfma_f32_16x16x32_bf16(Ah[rb], Bh[ctl], acc1[rb][ctl], 0, 0, 0);
                acc1[rb][ctl] = __builtin_amdgcn_mfma_f32_16x16x32_bf16(Ah[rb], Bl[ctl], acc1[rb][ctl], 0, 0, 0);
                acc1[rb][ctl] = __builtin_amdgcn_mfma_f32_16x16x32_bf16(Al[rb], Bh[ctl], acc1[rb][ctl], 0, 0, 0);
            }
    }

    // ---------------- bias + LN1 (cross-wave stats) + GELU -----------------
    {
        float b1v[4], g1v[4], be1v[4];
#pragma unroll
        for (int ctl = 0; ctl < 4; ++ctl) {
            int col = w * 64 + ctl * 16 + li;
            b1v[ctl] = b1[col]; g1v[ctl] = g1[col]; be1v[ctl] = be1[col];
        }
#pragma unroll
        for (int rb = 0; rb < 2; ++rb)
#pragma unroll
            for (int reg = 0; reg < 4; ++reg) {
                float s = 0.f, ss = 0.f;
#pragma unroll
                for (int ctl = 0; ctl < 4; ++ctl) {
                    float x = acc1[rb][ctl][reg] + b1v[ctl];
                    s += x; ss = fmaf(x, x, ss);
                }
#pragma unroll
                for (int m = 1; m <= 8; m <<= 1) {
                    s += __shfl_xor(s, m, 64);
                    ss += __shfl_xor(ss, m, 64);
                }
                if (li == 0) {
                    lnred[w][rb * 16 + lg * 4 + reg][0] = s;
                    lnred[w][rb * 16 + lg * 4 + reg][1] = ss;
                }
            }
        __syncthreads();  // B1
#pragma unroll
        for (int rb = 0; rb < 2; ++rb)
#pragma unroll
            for (int reg = 0; reg < 4; ++reg) {
                int row = rb * 16 + lg * 4 + reg;
                float s = lnred[0][row][0] + lnred[1][row][0] + lnred[2][row][0] + lnred[3][row][0];
                float ss = lnred[0][row][1] + lnred[1][row][1] + lnred[2][row][1] + lnred[3][row][1];
                float mean = s * (1.0f / 256.0f);
                float var = ss * (1.0f / 256.0f) - mean * mean;
                float rs = rsqrtf(var + 1e-5f);
#pragma unroll
                for (int ctl = 0; ctl < 4; ++ctl) {
                    float x = acc1[rb][ctl][reg] + b1v[ctl];
                    acc1[rb][ctl][reg] = gelu_exact((x - mean) * rs * g1v[ctl] + be1v[ctl]);
                }
            }
    }

    // ---------------- park FULL h (packed hi|lo u32); acc1 dies here -------
#pragma unroll
    for (int rb = 0; rb < 2; ++rb)
#pragma unroll
        for (int ctl = 0; ctl < 4; ++ctl) {
            unsigned w0, w1, w2, w3;
            pkpair(acc1[rb][ctl][0], acc1[rb][ctl][1], w0, w1);
            pkpair(acc1[rb][ctl][2], acc1[rb][ctl][3], w2, w3);
            int r0 = rb * 16 + lg * 4;
            int kc = w * 64 + ctl * 16 + li;
            hpk[r0 + 0][kc] = w0; hpk[r0 + 1][kc] = w1;
            hpk[r0 + 2][kc] = w2; hpk[r0 + 3][kc] = w3;
        }
    __syncthreads();  // B2

    // ---------------- MLP2: [32 x 256] @ [256 x 64-slice] (bf16x3) ---------
    f32x4 acc2[2][4];
#pragma unroll
    for (int rb = 0; rb < 2; ++rb)
#pragma unroll
        for (int ctl = 0; ctl < 4; ++ctl) acc2[rb][ctl] = (f32x4){0.f, 0.f, 0.f, 0.f};

#pragma unroll
    for (int q = 0; q < 8; ++q) {
        s16x8 Bh[4], Bl[4];
#pragma unroll
        for (int ctl = 0; ctl < 4; ++ctl)
            loadB(pk2, (ws4 + ctl) * 8 + q, l, Bh[ctl], Bl[ctl]);
#pragma unroll
        for (int rb = 0; rb < 2; ++rb) {
            const unsigned int* hp = &hpk[rb * 16 + li][q * 32 + lg * 8];
            int4 xa = *(const int4*)hp;
            int4 xb = *(const int4*)(hp + 4);
            unsigned x[8] = {(unsigned)xa.x, (unsigned)xa.y, (unsigned)xa.z, (unsigned)xa.w,
                             (unsigned)xb.x, (unsigned)xb.y, (unsigned)xb.z, (unsigned)xb.w};
            union { s16x8 s; unsigned w[4]; } H, L;
#pragma unroll
            for (int p = 0; p < 4; ++p) {
                H.w[p] = (x[2 * p] >> 16) | (x[2 * p + 1] & 0xffff0000u);
                L.w[p] = (x[2 * p] & 0xffffu) | (x[2 * p + 1] << 16);
            }
#pragma unroll
            for (int ctl = 0; ctl < 4; ++ctl) {
                acc2[rb][ctl] = __builtin_amdgcn_mfma_f32_16x16x32_bf16(H.s, Bh[ctl], acc2[rb][ctl], 0, 0, 0);
                acc2[rb][ctl] = __builtin_amdgcn_mfma_f32_16x16x32_bf16(H.s, Bl[ctl], acc2[rb][ctl], 0, 0, 0);
                acc2[rb][ctl] = __builtin_amdgcn_mfma_f32_16x16x32_bf16(L.s, Bh[ctl], acc2[rb][ctl], 0, 0, 0);
            }
        }
    }

    // ---------------- bias + LN2 (cross-wave stats) ------------------------
    float b2v[4], g2v[4], be2v[4];
#pragma unroll
    for (int ctl = 0; ctl < 4; ++ctl) {
        int col = w * 64 + ctl * 16 + li;
        b2v[ctl] = b2[col]; g2v[ctl] = g2[col]; be2v[ctl] = be2[col];
    }
#pragma unroll
    for (int rb = 0; rb < 2; ++rb)
#pragma unroll
        for (int reg = 0; reg < 4; ++reg) {
            float s = 0.f, ss = 0.f;
#pragma unroll
            for (int ctl = 0; ctl < 4; ++ctl) {
                float x = acc2[rb][ctl][reg] + b2v[ctl];
                s += x; ss = fmaf(x, x, ss);
            }
#pragma unroll
            for (int m = 1; m <= 8; m <<= 1) {
                s += __shfl_xor(s, m, 64);
                ss += __shfl_xor(ss, m, 64);
            }
            if (li == 0) {
                lnred[w][rb * 16 + lg * 4 + reg][0] = s;
                lnred[w][rb * 16 + lg * 4 + reg][1] = ss;
            }
        }
    __syncthreads();  // B3
#pragma unroll
    for (int rb = 0; rb < 2; ++rb)
#pragma unroll
        for (int reg = 0; reg < 4; ++reg) {
            int row = rb * 16 + lg * 4 + reg;
            float s = lnred[0][row][0] + lnred[1][row][0] + lnred[2][row][0] + lnred[3][row][0];
            float ss = lnred[0][row][1] + lnred[1][row][1] + lnred[2][row][1] + lnred[3][row][1];
            float mean = s * (1.0f / 256.0f);
            float var = ss * (1.0f / 256.0f) - mean * mean;
            float rs = rsqrtf(var + 1e-5f);
#pragma unroll
            for (int ctl = 0; ctl < 4; ++ctl) {
                float x = acc2[rb][ctl][reg] + b2v[ctl];
                acc2[rb][ctl][reg] = (x - mean) * rs * g2v[ctl] + be2v[ctl];
            }
        }

    // ---------------- max-pool / emit --------------------------------------
    if (K == 16) {  // two centers per block
#pragma unroll
        for (int rb = 0; rb < 2; ++rb)
#pragma unroll
            for (int ctl = 0; ctl < 4; ++ctl) {
                float mx = -3.4e38f;
#pragma unroll
                for (int reg = 0; reg < 4; ++reg) mx = fmaxf(mx, acc2[rb][ctl][reg]);
                mx = fmaxf(mx, __shfl_xor(mx, 16, 64));
                mx = fmaxf(mx, __shfl_xor(mx, 32, 64));
                if (lg == 0)
                    outf[(size_t)(blockIdx.x * 2 + rb) * TOK + w * 64 + ctl * 16 + li] = mx;
            }
    } else {  // K==32: one center; K==64: partial row (combined in token_mfma)
#pragma unroll
        for (int ctl = 0; ctl < 4; ++ctl) {
            float mx = -3.4e38f;
#pragma unroll
            for (int rb = 0; rb < 2; ++rb)
#pragma unroll
                for (int reg = 0; reg < 4; ++reg) mx = fmaxf(mx, acc2[rb][ctl][reg]);
            mx = fmaxf(mx, __shfl_xor(mx, 16, 64));
            mx = fmaxf(mx, __shfl_xor(mx, 32, 64));
            if (lg == 0)
                outf[(size_t)blockIdx.x * TOK + w * 64 + ctl * 16 + li] = mx;
        }
    }
}

// ---------------- Token MLP via bf16x3 MFMA, tok_in built on the fly -------
// Each 32-col k-chunk lies entirely in one segment:
//  ks 0..3: pf[center]; 4..11: sf0; 12..19: sf1; 20..27: max(sf2p even,odd);
//  28..30: PE.
__global__ __launch_bounds__(256, 2) void token_mfma(
    const float* __restrict__ pf, const int* __restrict__ center_idx,
    const float* __restrict__ pc, const float* __restrict__ sf0,
    const float* __restrict__ sf1, const float* __restrict__ sf2p,
    const unsigned short* __restrict__ pk1, const float* __restrict__ b1,
    const float* __restrict__ g1, const float* __restrict__ be1,
    const unsigned short* __restrict__ pk2, const float* __restrict__ b2,
    const float* __restrict__ g2, const float* __restrict__ be2,
    float* __restrict__ out) {
    __shared__ unsigned int hpk[32][260];
    __shared__ float lnred[4][32][2];
    const int w = threadIdx.x >> 6, l = threadIdx.x & 63;
    const int lg = l >> 4, li = l & 15;
    const int ws4 = 4 * w;
    const int rowbase = blockIdx.x * 32;

    int rowg[2];
    const float* pfc[2];
    float pcx[2], pcy[2], pcz[2];
#pragma unroll
    for (int rb = 0; rb < 2; ++rb) {
        int row = rowbase + rb * 16 + li;
        rowg[rb] = row;
        int b = row >> 9;
        int cidx = center_idx[row];
        pfc[rb] = pf + ((size_t)b * NPTS + cidx) * STEM;
        pcx[rb] = pc[(size_t)row * 3 + 0];
        pcy[rb] = pc[(size_t)row * 3 + 1];
        pcz[rb] = pc[(size_t)row * 3 + 2];
    }

    f32x4 acc1[2][4];
#pragma unroll
    for (int rb = 0; rb < 2; ++rb)
#pragma unroll
        for (int ctl = 0; ctl < 4; ++ctl) acc1[rb][ctl] = (f32x4){0.f, 0.f, 0.f, 0.f};

#pragma unroll 2
    for (int ks = 0; ks < 31; ++ks) {
        s16x8 Bh[4], Bl[4];
#pragma unroll
        for (int ctl = 0; ctl < 4; ++ctl)
            loadB(pk1, (ws4 + ctl) * 31 + ks, l, Bh[ctl], Bl[ctl]);
        s16x8 Ah[2], Al[2];
#pragma unroll
        for (int rb = 0; rb < 2; ++rb) {
            float v[8];
            if (ks < 20) {
                const float* src;
                if (ks < 4)       src = pfc[rb] + ks * 32 + lg * 8;
                else if (ks < 12) src = sf0 + (size_t)rowg[rb] * TOK + (ks - 4) * 32 + lg * 8;
                else              src = sf1 + (size_t)rowg[rb] * TOK + (ks - 12) * 32 + lg * 8;
                float4 f0 = *(const float4*)src;
                float4 f1 = *(const float4*)(src + 4);
                v[0] = f0.x; v[1] = f0.y; v[2] = f0.z; v[3] = f0.w;
                v[4] = f1.x; v[5] = f1.y; v[6] = f1.z; v[7] = f1.w;
            } else if (ks < 28) {
                // sf2 = max of the two K=64 partial rows
                const float* sa = sf2p + ((size_t)rowg[rb] * 2) * TOK + (ks - 20) * 32 + lg * 8;
                const float* sb = sa + TOK;
                float4 a0 = *(const float4*)sa;
                float4 a1 = *(const float4*)(sa + 4);
                float4 b0 = *(const float4*)sb;
                float4 b1 = *(const float4*)(sb + 4);
                v[0] = fmaxf(a0.x, b0.x); v[1] = fmaxf(a0.y, b0.y);
                v[2] = fmaxf(a0.z, b0.z); v[3] = fmaxf(a0.w, b0.w);
                v[4] = fmaxf(a1.x, b1.x); v[5] = fmaxf(a1.y, b1.y);
                v[6] = fmaxf(a1.z, b1.z); v[7] = fmaxf(a1.w, b1.w);
            } else {
                float c = (ks == 28) ? pcx[rb] : ((ks == 29) ? pcy[rb] : pcz[rb]);
#pragma unroll
                for (int j = 0; j < 8; ++j) {
                    float fr = (lg & 1) ? FR15c[8 + j] : FR15c[j];
                    float ang = c * fr;
                    v[j] = (lg < 2) ? __sinf(ang) : __cosf(ang);
                }
            }
            bsplit8(v, Ah[rb], Al[rb]);
        }
#pragma unroll
        for (int ctl = 0; ctl < 4; ++ctl)
#pragma unroll
            for (int rb = 0; rb < 2; ++rb) {
                acc1[rb][ctl] = __builtin_amdgcn_mfma_f32_16x16x32_bf16(Ah[rb], Bh[ctl], acc1[rb][ctl], 0, 0, 0);
                acc1[rb][ctl] = __builtin_amdgcn_mfma_f32_16x16x32_bf16(Ah[rb], Bl[ctl], acc1[rb][ctl], 0, 0, 0);
                acc1[rb][ctl] = __builtin_amdgcn_mfma_f32_16x16x32_bf16(Al[rb], Bh[ctl], acc1[rb][ctl], 0, 0, 0);
            }
    }

    {
        float b1v[4], g1v[4], be1v[4];
#pragma unroll
        for (int ctl = 0; ctl < 4; ++ctl) {
            int col = w * 64 + ctl * 16 + li;
            b1v[ctl] = b1[col]; g1v[ctl] = g1[col]; be1v[ctl] = be1[col];
        }
#pragma unroll
        for (int rb = 0; rb < 2; ++rb)
#pragma unroll
            for (int reg = 0; reg < 4; ++reg) {
                float s = 0.f, ss = 0.f;
#pragma unroll
                for (int ctl = 0; ctl < 4; ++ctl) {
                    float x = acc1[rb][ctl][reg] + b1v[ctl];
                    s += x; ss = fmaf(x, x, ss);
                }
#pragma unroll
                for (int m = 1; m <= 8; m <<= 1) {
                    s += __shfl_xor(s, m, 64);
                    ss += __shfl_xor(ss, m, 64);
                }
                if (li == 0) {
                    lnred[w][rb * 16 + lg * 4 + reg][0] = s;
                    lnred[w][rb * 16 + lg * 4 + reg][1] = ss;
                }
            }
        __syncthreads();
#pragma unroll
        for (int rb = 0; rb < 2; ++rb)
#pragma unroll
            for (int reg = 0; reg < 4; ++reg) {
                int row = rb * 16 + lg * 4 + reg;
                float s = lnred[0][row][0] + lnred[1][row][0] + lnred[2][row][0] + lnred[3][row][0];
                float ss = lnred[0][row][1] + lnred[1][row][1] + lnred[2][row][1] + lnred[3][row][1];
                float mean = s * (1.0f / 256.0f);
                float var = ss * (1.0f / 256.0f) - mean * mean;
                float rs = rsqrtf(var + 1e-5f);
#pragma unroll
                for (int ctl = 0; ctl < 4; ++ctl) {
                    float x = acc1[rb][ctl][reg] + b1v[ctl];
                    acc1[rb][ctl][reg] = gelu_exact((x - mean) * rs * g1v[ctl] + be1v[ctl]);
                }
            }
    }

#pragma unroll
    for (int rb = 0; rb < 2; ++rb)
#pragma unroll
        for (int ctl = 0; ctl < 4; ++ctl) {
            unsigned w0, w1, w2, w3;
            pkpair(acc1[rb][ctl][0], acc1[rb][ctl][1], w0, w1);
            pkpair(acc1[rb][ctl][2], acc1[rb][ctl][3], w2, w3);
            int r0 = rb * 16 + lg * 4;
            int kc = w * 64 + ctl * 16 + li;
            hpk[r0 + 0][kc] = w0; hpk[r0 + 1][kc] = w1;
            hpk[r0 + 2][kc] = w2; hpk[r0 + 3][kc] = w3;
        }
    __syncthreads();

    f32x4 acc2[2][4];
#pragma unroll
    for (int rb = 0; rb < 2; ++rb)
#pragma unroll
        for (int ctl = 0; ctl < 4; ++ctl) acc2[rb][ctl] = (f32x4){0.f, 0.f, 0.f, 0.f};
#pragma unroll
    for (int q = 0; q < 8; ++q) {
        s16x8 Bh[4], Bl[4];
#pragma unroll
        for (int ctl = 0; ctl < 4; ++ctl)
            loadB(pk2, (ws4 + ctl) * 8 + q, l, Bh[ctl], Bl[ctl]);
#pragma unroll
        for (int rb = 0; rb < 2; ++rb) {
            const unsigned int* hp = &hpk[rb * 16 + li][q * 32 + lg * 8];
            int4 xa = *(const int4*)hp;
            int4 xb = *(const int4*)(hp + 4);
            unsigned x[8] = {(unsigned)xa.x, (unsigned)xa.y, (unsigned)xa.z, (unsigned)xa.w,
                             (unsigned)xb.x, (unsigned)xb.y, (unsigned)xb.z, (unsigned)xb.w};
            union { s16x8 s; unsigned w[4]; } H, L;
#pragma unroll
            for (int p = 0; p < 4; ++p) {
                H.w[p] = (x[2 * p] >> 16) | (x[2 * p + 1] & 0xffff0000u);
                L.w[p] = (x[2 * p] & 0xffffu) | (x[2 * p + 1] << 16);
            }
#pragma unroll
            for (int ctl = 0; ctl < 4; ++ctl) {
                acc2[rb][ctl] = __builtin_amdgcn_mfma_f32_16x16x32_bf16(H.s, Bh[ctl], acc2[rb][ctl], 0, 0, 0);
                acc2[rb][ctl] = __builtin_amdgcn_mfma_f32_16x16x32_bf16(H.s, Bl[ctl], acc2[rb][ctl], 0, 0, 0);
                acc2[rb][ctl] = __builtin_amdgcn_mfma_f32_16x16x32_bf16(L.s, Bh[ctl], acc2[rb][ctl], 0, 0, 0);
            }
        }
    }

    float b2v[4], g2v[4], be2v[4];
#pragma unroll
    for (int ctl = 0; ctl < 4; ++ctl) {
        int col = w * 64 + ctl * 16 + li;
        b2v[ctl] = b2[col]; g2v[ctl] = g2[col]; be2v[ctl] = be2[col];
    }
#pragma unroll
    for (int rb = 0; rb < 2; ++rb)
#pragma unroll
        for (int reg = 0; reg < 4; ++reg) {
            float s = 0.f, ss = 0.f;
#pragma unroll
            for (int ctl = 0; ctl < 4; ++ctl) {
                float x = acc2[rb][ctl][reg] + b2v[ctl];
                s += x; ss = fmaf(x, x, ss);
            }
#pragma unroll
            for (int m = 1; m <= 8; m <<= 1) {
                s += __shfl_xor(s, m, 64);
                ss += __shfl_xor(ss, m, 64);
            }
            if (li == 0) {
                lnred[w][rb * 16 + lg * 4 + reg][0] = s;
                lnred[w][rb * 16 + lg * 4 + reg][1] = ss;
            }
        }
    __syncthreads();
#pragma unroll
    for (int rb = 0; rb < 2; ++rb)
#pragma unroll
        for (int reg = 0; reg < 4; ++reg) {
            int row = rb * 16 + lg * 4 + reg;
            float s = lnred[0][row][0] + lnred[1][row][0] + lnred[2][row][0] + lnred[3][row][0];
            float ss = lnred[0][row][1] + lnred[1][row][1] + lnred[2][row][1] + lnred[3][row][1];
            float mean = s * (1.0f / 256.0f);
            float var = ss * (1.0f / 256.0f) - mean * mean;
            float rs = rsqrtf(var + 1e-5f);
#pragma unroll
            for (int ctl = 0; ctl < 4; ++ctl) {
                float x = acc2[rb][ctl][reg] + b2v[ctl];
                float v = (x - mean) * rs * g2v[ctl] + be2v[ctl];
                out[(size_t)(rowbase + row) * TOK + w * 64 + ctl * 16 + li] = v;
            }
        }
}

extern "C" void kernel_launch(void* const* d_in, const int* in_sizes, int n_in,
                              void* d_out, int out_size, void* d_ws, size_t ws_size,
                              hipStream_t stream) {
    const float* xyz  = (const float*)d_in[0];
    const float* pf   = (const float*)d_in[1];
    const float* sW1  = (const float*)d_in[2];
    const float* sb1  = (const float*)d_in[3];
    const float* sg1  = (const float*)d_in[4];
    const float* sbe1 = (const float*)d_in[5];
    const float* sW2  = (const float*)d_in[6];
    const float* sb2  = (const float*)d_in[7];
    const float* sg2  = (const float*)d_in[8];
    const float* sbe2 = (const float*)d_in[9];
    const float* tW1  = (const float*)d_in[10];
    const float* tb1  = (const float*)d_in[11];
    const float* tg1  = (const float*)d_in[12];
    const float* tbe1 = (const float*)d_in[13];
    const float* tW2  = (const float*)d_in[14];
    const float* tb2  = (const float*)d_in[15];
    const float* tg2  = (const float*)d_in[16];
    const float* tbe2 = (const float*)d_in[17];

    float* out_tok = (float*)d_out;
    float* out_pc  = out_tok + (size_t)BATCH * NCTR * TOK;

    char* ws = (char*)d_ws;
    int* center_idx = (int*)ws;   ws += (size_t)BATCH * NCTR * 4;
    float* pc_ws    = (float*)ws; ws += (size_t)BATCH * NCTR * 3 * 4;
    int* nbr0       = (int*)ws;   ws += (size_t)BATCH * NCTR * 16 * 4;
    int* nbr1       = (int*)ws;   ws += (size_t)BATCH * NCTR * 32 * 4;
    int* nbr2       = (int*)ws;   ws += (size_t)BATCH * NCTR * 64 * 4;
    float* sf0      = (float*)ws; ws += (size_t)BATCH * NCTR * TOK * 4;
    float* sf1      = (float*)ws; ws += (size_t)BATCH * NCTR * TOK * 4;
    float* sf2p     = (float*)ws; ws += (size_t)BATCH * NCTR * 2 * TOK * 4;  // K=64 partials
    const size_t PK1_S  = 16 * 5 * 64 * 16;    // ushorts per scale (sW1)
    const size_t PK2_S  = 16 * 8 * 64 * 16;    // ushorts per scale (sW2)
    const size_t PKT1_S = 16 * 31 * 64 * 16;   // ushorts (tW1)
    const size_t PKT2_S = 16 * 8 * 64 * 16;    // ushorts (tW2)
    unsigned short* pkW1 = (unsigned short*)ws; ws += 3 * PK1_S * 2;
    unsigned short* pkW2 = (unsigned short*)ws; ws += 3 * PK2_S * 2;
    unsigned short* pkT1 = (unsigned short*)ws; ws += PKT1_S * 2;
    unsigned short* pkT2 = (unsigned short*)ws; ws += PKT2_S * 2;

    {
        dim3 gp1((16 * 5 * 64 + 255) / 256, 3);
        pack_w<<<gp1, 256, 0, stream>>>(sW1, pkW1, D_IN, 5);
        dim3 gp2((16 * 8 * 64 + 255) / 256, 3);
        pack_w<<<gp2, 256, 0, stream>>>(sW2, pkW2, TOK, 8);
        dim3 gpt1((16 * 31 * 64 + 255) / 256, 1);
        pack_w<<<gpt1, 256, 0, stream>>>(tW1, pkT1, D_TOK, 31);
        dim3 gpt2((16 * 8 * 64 + 255) / 256, 1);
        pack_w<<<gpt2, 256, 0, stream>>>(tW2, pkT2, TOK, 8);
    }

    fps_kernel<<<BATCH, 1024, 0, stream>>>(xyz, center_idx, pc_ws, out_pc);

    ballq_kernel<16><<<BATCH * NCTR / 4, 256, 0, stream>>>(xyz, pc_ws, nbr0, (float)(0.1 * 0.1));
    ballq_kernel<32><<<BATCH * NCTR / 4, 256, 0, stream>>>(xyz, pc_ws, nbr1, (float)(0.2 * 0.2));
    ballq_kernel<64><<<BATCH * NCTR / 4, 256, 0, stream>>>(xyz, pc_ws, nbr2, (float)(0.4 * 0.4));

    // 32 rows per block
    scale_mfma<16><<<(BATCH * NCTR * 16) / 32, 256, 0, stream>>>(
        xyz, pf, pkW1 + 0 * PK1_S, sb1 + 0 * TOK, sg1 + 0 * TOK, sbe1 + 0 * TOK,
        pkW2 + 0 * PK2_S, sb2 + 0 * TOK, sg2 + 0 * TOK, sbe2 + 0 * TOK,
        nbr0, pc_ws, sf0);
    scale_mfma<32><<<(BATCH * NCTR * 32) / 32, 256, 0, stream>>>(
        xyz, pf, pkW1 + 1 * PK1_S, sb1 + 1 * TOK, sg1 + 1 * TOK, sbe1 + 1 * TOK,
        pkW2 + 1 * PK2_S, sb2 + 1 * TOK, sg2 + 1 * TOK, sbe2 + 1 * TOK,
        nbr1, pc_ws, sf1);
    scale_mfma<64><<<(BATCH * NCTR * 64) / 32, 256, 0, stream>>>(
        xyz, pf, pkW1 + 2 * PK1_S, sb1 + 2 * TOK, sg1 + 2 * TOK, sbe1 + 2 * TOK,
        pkW2 + 2 * PK2_S, sb2 + 2 * TOK, sg2 + 2 * TOK, sbe2 + 2 * TOK,
        nbr2, pc_ws, sf2p);

    token_mfma<<<(BATCH * NCTR) / 32, 256, 0, stream>>>(
        pf, center_idx, pc_ws, sf0, sf1, sf2p,
        pkT1, tb1, tg1, tbe1, pkT2, tb2, tg2, tbe2, out_tok);
}

// Round 11
// 1471.021 us; speedup vs baseline: 1.1734x; 1.1734x over previous
//
#include <hip/hip_runtime.h>
#include <math.h>

#define BATCH 16
#define NPTS  4096
#define NCTR  512
#define STEM  128
#define TOK   256
#define D_IN  155   // 128 + 3 + 24
#define D_TOK 992   // 128 + 3*256 + 96

typedef short s16x8 __attribute__((ext_vector_type(8)));
typedef float f32x4 __attribute__((ext_vector_type(4)));

// 10000^(-i/15), i=0..15 (token-PE frequencies)
static constexpr float FR15c[16] = {
    1.0f, 0.5411695265464638f, 0.2928644487857941f, 0.15848931670188904f,
    0.08576958626508713f, 0.04641588851809502f, 0.02511886507272720f, 0.01359356392547488f,
    0.007356422487646341f, 0.003981071710586548f, 0.002154434798285365f, 0.001165914465673268f,
    0.0006309573450125754f, 0.0003414548910222948f, 0.0001847849769866168f, 0.0001f};

__device__ __forceinline__ unsigned short f2bf(float f) {
    unsigned u = __float_as_uint(f);
    u += 0x7FFF + ((u >> 16) & 1);
    return (unsigned short)(u >> 16);
}
__device__ __forceinline__ float bf2f(unsigned short b) {
    return __uint_as_float(((unsigned)b) << 16);
}

// split 8 f32 -> hi/lo bf16 fragments via v_cvt_pk_bf16_f32 (RNE)
__device__ __forceinline__ void bsplit8(const float* v, s16x8& hi, s16x8& lo) {
    union { s16x8 s; unsigned w[4]; } H, L;
#pragma unroll
    for (int p = 0; p < 4; ++p) {
        unsigned hp, lp;
        asm("v_cvt_pk_bf16_f32 %0, %1, %2" : "=v"(hp) : "v"(v[2 * p]), "v"(v[2 * p + 1]));
        float r0 = v[2 * p]     - __uint_as_float(hp << 16);
        float r1 = v[2 * p + 1] - __uint_as_float(hp & 0xffff0000u);
        asm("v_cvt_pk_bf16_f32 %0, %1, %2" : "=v"(lp) : "v"(r0), "v"(r1));
        H.w[p] = hp; L.w[p] = lp;
    }
    hi = H.s; lo = L.s;
}

// pack two f32 into two (hi16|lo16) u32 words
__device__ __forceinline__ void pkpair(float v0, float v1, unsigned& w0, unsigned& w1) {
    unsigned hp, lp;
    asm("v_cvt_pk_bf16_f32 %0, %1, %2" : "=v"(hp) : "v"(v0), "v"(v1));
    float r0 = v0 - __uint_as_float(hp << 16);
    float r1 = v1 - __uint_as_float(hp & 0xffff0000u);
    asm("v_cvt_pk_bf16_f32 %0, %1, %2" : "=v"(lp) : "v"(r0), "v"(r1));
    w0 = (hp << 16) | (lp & 0xffffu);
    w1 = (hp & 0xffff0000u) | (lp >> 16);
}

// B-fragment direct load: global (L2-hot) -> VGPR, 16B hi + 16B lo per lane
__device__ __forceinline__ void loadB(const unsigned short* __restrict__ pk,
                                      int frag, int l, s16x8& bh, s16x8& bl) {
    const unsigned short* p = pk + (size_t)frag * 1024 + (size_t)l * 8;
    bh = *(const s16x8*)p;
    bl = *(const s16x8*)(p + 512);
}

// fast exact-GELU: A&S 7.1.26 erf (|abs err| < 2e-7)
__device__ __forceinline__ float gelu_exact(float x) {
    float z = x * 0.70710678118654752f;
    float a = fabsf(z);
    float t = __builtin_amdgcn_rcpf(fmaf(0.3275911f, a, 1.0f));
    float p = fmaf(1.061405429f, t, -1.453152027f);
    p = fmaf(p, t, 1.421413741f);
    p = fmaf(p, t, -0.284496736f);
    p = fmaf(p, t, 0.254829592f);
    p = p * t;
    float e = __expf(-z * z);
    float y = fmaf(-p, e, 1.0f);
    y = (z < 0.0f) ? -y : y;
    return 0.5f * x * (1.0f + y);
}

// exact, non-contracted squared distance to match numpy f32 rounding
__device__ __forceinline__ float sq3(float ax, float ay, float az,
                                     float bx, float by, float bz) {
    float dx = __fsub_rn(ax, bx);
    float dy = __fsub_rn(ay, by);
    float dz = __fsub_rn(az, bz);
    float d = __fmul_rn(dx, dx);
    d = __fadd_rn(d, __fmul_rn(dy, dy));
    d = __fadd_rn(d, __fmul_rn(dz, dz));
    return d;
}

// argmax-combine one DPP row_ror step: rotation is valid for a total-order
// max reduce (associative+commutative); comparator keeps (val desc, idx asc).
// DPP is register-lane movement -- no LDS pipe, ~10cy/level vs ~120cy shfl.
template <int CTRL>
__device__ __forceinline__ void dpp_amax(float& bv, int& bi) {
    int vv = __builtin_amdgcn_update_dpp(__float_as_int(bv), __float_as_int(bv),
                                         CTRL, 0xF, 0xF, false);
    int oi = __builtin_amdgcn_update_dpp(bi, bi, CTRL, 0xF, 0xF, false);
    float ov = __int_as_float(vv);
    if (ov > bv || (ov == bv && oi < bi)) { bv = ov; bi = oi; }
}
// full 16-lane-row argmax reduce (4 levels: ror 8,4,2,1)
__device__ __forceinline__ void row_amax16(float& bv, int& bi) {
    dpp_amax<0x128>(bv, bi);   // row_ror:8
    dpp_amax<0x124>(bv, bi);   // row_ror:4
    dpp_amax<0x122>(bv, bi);   // row_ror:2
    dpp_amax<0x121>(bv, bi);   // row_ror:1
}

// ---------------- FPS: 256 threads, DPP row-reduce, 1 barrier/step ---------
__global__ __launch_bounds__(256) void fps_kernel(const float* __restrict__ xyz,
                                                  int* __restrict__ center_idx,
                                                  float* __restrict__ pc_ws,
                                                  float* __restrict__ pc_out) {
    int b = blockIdx.x;
    int t = threadIdx.x;
    const int w = t >> 6, lane = t & 63;
    const float* X = xyz + (size_t)b * NPTS * 3;
    __shared__ __align__(16) float sxyz[NPTS * 3];  // 48 KB
    __shared__ float swv[2][16];
    __shared__ int   swi[2][16];
    __shared__ int   hist[NCTR];                    // 2 KB
    {
        const float4* src = (const float4*)X;
        float4* dst = (float4*)sxyz;
        for (int i = t; i < NPTS * 3 / 4; i += 256) dst[i] = src[i];
    }
    __syncthreads();
    float px[16], py[16], pz[16], dist[16];
#pragma unroll
    for (int j = 0; j < 16; ++j) {
        int i = t + 256 * j;
        px[j] = sxyz[i * 3 + 0];
        py[j] = sxyz[i * 3 + 1];
        pz[j] = sxyz[i * 3 + 2];
        dist[j] = 1e10f;
    }
    int far = 0;
    for (int s = 0; s < NCTR; ++s) {
        if (t == 0) hist[s] = far;
        float cx = sxyz[far * 3 + 0];
        float cy = sxyz[far * 3 + 1];
        float cz = sxyz[far * 3 + 2];
        float bv = -1.0f;
        int bi = 0;
#pragma unroll
        for (int j = 0; j < 16; ++j) {
            float d = sq3(px[j], py[j], pz[j], cx, cy, cz);
            float nd = fminf(dist[j], d);
            dist[j] = nd;
            if (nd > bv) { bv = nd; bi = t + 256 * j; }  // strict >: earliest idx
        }
        // 16-lane-row reduce via DPP (no LDS pipe)
        row_amax16(bv, bi);
        const int p = s & 1;
        if ((lane & 15) == 0) {
            int r = w * 4 + (lane >> 4);
            swv[p][r] = bv; swi[p][r] = bi;
        }
        __syncthreads();
        // combine 16 row-partials: one LDS read + 4 DPP levels
        bv = swv[p][lane & 15];
        bi = swi[p][lane & 15];
        row_amax16(bv, bi);
        far = bi;
    }
    __syncthreads();
    for (int s = t; s < NCTR; s += 256) {
        int idx = hist[s];
        center_idx[b * NCTR + s] = idx;
        float cx = sxyz[idx * 3], cy = sxyz[idx * 3 + 1], cz = sxyz[idx * 3 + 2];
        size_t po = (size_t)(b * NCTR + s) * 3;
        pc_ws[po] = cx; pc_ws[po + 1] = cy; pc_ws[po + 2] = cz;
        pc_out[po] = cx; pc_out[po + 1] = cy; pc_out[po + 2] = cz;
    }
}

// ---------------- Ball query (unchanged) ----------------------------------
template <int K>
__global__ __launch_bounds__(256) void ballq_kernel(const float* __restrict__ xyz,
                                                    const float* __restrict__ pc,
                                                    int* __restrict__ nbr,
                                                    float rr) {
    int cid = blockIdx.x * 4 + (threadIdx.x >> 6);
    int lane = threadIdx.x & 63;
    int b = cid >> 9;
    const float* X = xyz + (size_t)b * NPTS * 3;
    float cx = pc[(size_t)cid * 3 + 0];
    float cy = pc[(size_t)cid * 3 + 1];
    float cz = pc[(size_t)cid * 3 + 2];
    int cnt = 0, first = 0;
    bool have_first = false;
    long long base = (long long)cid * K;
    for (int it = 0; it < NPTS / 64; ++it) {
        int i = it * 64 + lane;
        float d = sq3(cx, cy, cz, X[i * 3], X[i * 3 + 1], X[i * 3 + 2]);
        bool ok = d <= rr;
        unsigned long long mask = __ballot(ok);
        if (!have_first && mask) {
            first = it * 64 + (int)__builtin_ctzll(mask);
            have_first = true;
        }
        int pos = cnt + (int)__popcll(mask & ((1ull << lane) - 1ull));
        if (ok && pos < K) nbr[base + pos] = i;
        cnt += (int)__popcll(mask);
        if (cnt >= K) break;
    }
    int fill = cnt < K ? cnt : K;
    for (int j = fill + lane; j < K; j += 64) nbr[base + j] = first;
}

// ---------------- Weight pack: hi-plane/lo-plane bf16 MFMA B-frags --------
__global__ __launch_bounds__(256) void pack_w(const float* __restrict__ Wbase,
                                              unsigned short* __restrict__ out,
                                              int Kdim, int KS) {
    int s = blockIdx.y;
    const float* W = Wbase + (size_t)s * Kdim * TOK;
    unsigned short* o = out + (size_t)s * 16 * KS * 64 * 16;
    int tid = blockIdx.x * 256 + threadIdx.x;
    if (tid >= 16 * KS * 64) return;
    int lane = tid & 63;
    int frag = tid >> 6;
    int ks = frag % KS;
    int ct = frag / KS;
    int col = ct * 16 + (lane & 15);
    int k0 = ks * 32 + (lane >> 4) * 8;
    unsigned short* hi = o + (size_t)frag * 1024 + lane * 8;
    unsigned short* lo = hi + 512;
#pragma unroll
    for (int j = 0; j < 8; ++j) {
        int k = k0 + j;
        float v = (k < Kdim) ? W[(size_t)k * TOK + col] : 0.0f;
        unsigned short h = f2bf(v);
        hi[j] = h;
        lo[j] = f2bf(v - bf2f(h));
    }
}

// ---------------- Per-scale grouped MLP via bf16x3 MFMA --------------------
// 32-row blocks, ONE-PASS skeleton (proven round-6/round-9 structure).
// K=64 centers span two blocks: each block emits a PARTIAL max row to
// sf2p[2*c+half]; token_mfma combines with fmaxf.
template <int K>
__global__ __launch_bounds__(256, 2) void scale_mfma(
    const float* __restrict__ xyz, const float* __restrict__ pf,
    const unsigned short* __restrict__ pk1, const float* __restrict__ b1,
    const float* __restrict__ g1, const float* __restrict__ be1,
    const unsigned short* __restrict__ pk2, const float* __restrict__ b2,
    const float* __restrict__ g2, const float* __restrict__ be2,
    const int* __restrict__ nbr, const float* __restrict__ pc,
    float* __restrict__ outf) {
    __shared__ unsigned int hpk[32][260];   // 33 KB packed-bf16 h (32 rows)
    __shared__ float lnred[4][32][2];       // 1 KB
    const int w = threadIdx.x >> 6, l = threadIdx.x & 63;
    const int lg = l >> 4, li = l & 15;
    const int ws4 = 4 * w;

    int nb[2];
    float relx[2], rely[2], relz[2];
#pragma unroll
    for (int rb = 0; rb < 2; ++rb) {
        int row_g = blockIdx.x * 32 + rb * 16 + li;
        int c = (blockIdx.x * 32 + rb * 16) / K;   // li never crosses a center
        int b = c >> 9;
        int n = nbr[row_g];
        nb[rb] = b * NPTS + n;
        const float* X = xyz + (size_t)nb[rb] * 3;
        const float* C = pc + (size_t)c * 3;
        relx[rb] = __fsub_rn(X[0], C[0]);
        rely[rb] = __fsub_rn(X[1], C[1]);
        relz[rb] = __fsub_rn(X[2], C[2]);
    }

    // ---------------- MLP1: [32 x 160] @ [160 x 64-slice] (bf16x3) --------
    f32x4 acc1[2][4];
#pragma unroll
    for (int rb = 0; rb < 2; ++rb)
#pragma unroll
        for (int ctl = 0; ctl < 4; ++ctl) acc1[rb][ctl] = (f32x4){0.f, 0.f, 0.f, 0.f};

#pragma unroll
    for (int ks = 0; ks < 5; ++ks) {
        s16x8 Bh[4], Bl[4];
#pragma unroll
        for (int ctl = 0; ctl < 4; ++ctl)
            loadB(pk1, (ws4 + ctl) * 5 + ks, l, Bh[ctl], Bl[ctl]);
        s16x8 Ah[2], Al[2];
#pragma unroll
        for (int rb = 0; rb < 2; ++rb) {
            float v[8];
            if (ks < 4) {
                const float* src = pf + (size_t)nb[rb] * STEM + ks * 32 + lg * 8;
                float4 f0 = *(const float4*)src;
                float4 f1 = *(const float4*)(src + 4);
                v[0] = f0.x; v[1] = f0.y; v[2] = f0.z; v[3] = f0.w;
                v[4] = f1.x; v[5] = f1.y; v[6] = f1.z; v[7] = f1.w;
            } else {
#pragma unroll
                for (int j = 0; j < 8; ++j) {
                    int ch = lg * 8 + j;
                    float val = 0.0f;
                    if (ch < 3) {
                        val = (ch == 0) ? relx[rb] : ((ch == 1) ? rely[rb] : relz[rb]);
                    } else if (ch < 27) {
                        int rem = ch - 3;
                        int axis = rem >> 3, r8 = rem & 7;
                        int fi = (r8 < 4) ? r8 : r8 - 4;
                        float fr = (fi == 0) ? 1.0f
                                  : (fi == 1) ? 0.046415888336127795f
                                  : (fi == 2) ? 0.0021544346900318843f : 1e-4f;
                        float rl = (axis == 0) ? relx[rb] : ((axis == 1) ? rely[rb] : relz[rb]);
                        float ang = rl * fr;
                        val = (r8 < 4) ? __sinf(ang) : __cosf(ang);
                    }
                    v[j] = val;
                }
            }
            bsplit8(v, Ah[rb], Al[rb]);
        }
#pragma unroll
        for (int ctl = 0; ctl < 4; ++ctl)
#pragma unroll
            for (int rb = 0; rb < 2; ++rb) {
                acc1[rb][ctl] = __builtin_amdgcn_mfma_f32_16x16x32_bf16(Ah[rb], Bh[ctl], acc1[rb][ctl], 0, 0, 0);
                acc1[rb][ctl] = __builtin_amdgcn_mfma_f32_16x16x32_bf16(Ah[rb], Bl[ctl], acc1[rb][ctl], 0, 0, 0);
                acc1[rb][ctl] = __builtin_amdgcn_mfma_f32_16x16x32_bf16(Al[rb], Bh[ctl], acc1[rb][ctl], 0, 0, 0);
            }
    }

    // ---------------- bias + LN1 (cross-wave stats) + GELU -----------------
    {
        float b1v[4], g1v[4], be1v[4];
#pragma unroll
        for (int ctl = 0; ctl < 4; ++ctl) {
            int col = w * 64 + ctl * 16 + li;
            b1v[ctl] = b1[col]; g1v[ctl] = g1[col]; be1v[ctl] = be1[col];
        }
#pragma unroll
        for (int rb = 0; rb < 2; ++rb)
#pragma unroll
            for (int reg = 0; reg < 4; ++reg) {
                float s = 0.f, ss = 0.f;
#pragma unroll
                for (int ctl = 0; ctl < 4; ++ctl) {
                    float x = acc1[rb][ctl][reg] + b1v[ctl];
                    s += x; ss = fmaf(x, x, ss);
                }
#pragma unroll
                for (int m = 1; m <= 8; m <<= 1) {
                    s += __shfl_xor(s, m, 64);
                    ss += __shfl_xor(ss, m, 64);
                }
                if (li == 0) {
                    lnred[w][rb * 16 + lg * 4 + reg][0] = s;
                    lnred[w][rb * 16 + lg * 4 + reg][1] = ss;
                }
            }
        __syncthreads();  // B1
#pragma unroll
        for (int rb = 0; rb < 2; ++rb)
#pragma unroll
            for (int reg = 0; reg < 4; ++reg) {
                int row = rb * 16 + lg * 4 + reg;
                float s = lnred[0][row][0] + lnred[1][row][0] + lnred[2][row][0] + lnred[3][row][0];
                float ss = lnred[0][row][1] + lnred[1][row][1] + lnred[2][row][1] + lnred[3][row][1];
                float mean = s * (1.0f / 256.0f);
                float var = ss * (1.0f / 256.0f) - mean * mean;
                float rs = rsqrtf(var + 1e-5f);
#pragma unroll
                for (int ctl = 0; ctl < 4; ++ctl) {
                    float x = acc1[rb][ctl][reg] + b1v[ctl];
                    acc1[rb][ctl][reg] = gelu_exact((x - mean) * rs * g1v[ctl] + be1v[ctl]);
                }
            }
    }

    // ---------------- park FULL h (packed hi|lo u32); acc1 dies here -------
#pragma unroll
    for (int rb = 0; rb < 2; ++rb)
#pragma unroll
        for (int ctl = 0; ctl < 4; ++ctl) {
            unsigned w0, w1, w2, w3;
            pkpair(acc1[rb][ctl][0], acc1[rb][ctl][1], w0, w1);
            pkpair(acc1[rb][ctl][2], acc1[rb][ctl][3], w2, w3);
            int r0 = rb * 16 + lg * 4;
            int kc = w * 64 + ctl * 16 + li;
            hpk[r0 + 0][kc] = w0; hpk[r0 + 1][kc] = w1;
            hpk[r0 + 2][kc] = w2; hpk[r0 + 3][kc] = w3;
        }
    __syncthreads();  // B2

    // ---------------- MLP2: [32 x 256] @ [256 x 64-slice] (bf16x3) ---------
    f32x4 acc2[2][4];
#pragma unroll
    for (int rb = 0; rb < 2; ++rb)
#pragma unroll
        for (int ctl = 0; ctl < 4; ++ctl) acc2[rb][ctl] = (f32x4){0.f, 0.f, 0.f, 0.f};

#pragma unroll
    for (int q = 0; q < 8; ++q) {
        s16x8 Bh[4], Bl[4];
#pragma unroll
        for (int ctl = 0; ctl < 4; ++ctl)
            loadB(pk2, (ws4 + ctl) * 8 + q, l, Bh[ctl], Bl[ctl]);
#pragma unroll
        for (int rb = 0; rb < 2; ++rb) {
            const unsigned int* hp = &hpk[rb * 16 + li][q * 32 + lg * 8];
            int4 xa = *(const int4*)hp;
            int4 xb = *(const int4*)(hp + 4);
            unsigned x[8] = {(unsigned)xa.x, (unsigned)xa.y, (unsigned)xa.z, (unsigned)xa.w,
                             (unsigned)xb.x, (unsigned)xb.y, (unsigned)xb.z, (unsigned)xb.w};
            union { s16x8 s; unsigned w[4]; } H, L;
#pragma unroll
            for (int p = 0; p < 4; ++p) {
                H.w[p] = (x[2 * p] >> 16) | (x[2 * p + 1] & 0xffff0000u);
                L.w[p] = (x[2 * p] & 0xffffu) | (x[2 * p + 1] << 16);
            }
#pragma unroll
            for (int ctl = 0; ctl < 4; ++ctl) {
                acc2[rb][ctl] = __builtin_amdgcn_mfma_f32_16x16x32_bf16(H.s, Bh[ctl], acc2[rb][ctl], 0, 0, 0);
                acc2[rb][ctl] = __builtin_amdgcn_mfma_f32_16x16x32_bf16(H.s, Bl[ctl], acc2[rb][ctl], 0, 0, 0);
                acc2[rb][ctl] = __builtin_amdgcn_mfma_f32_16x16x32_bf16(L.s, Bh[ctl], acc2[rb][ctl], 0, 0, 0);
            }
        }
    }

    // ---------------- bias + LN2 (cross-wave stats) ------------------------
    float b2v[4], g2v[4], be2v[4];
#pragma unroll
    for (int ctl = 0; ctl < 4; ++ctl) {
        int col = w * 64 + ctl * 16 + li;
        b2v[ctl] = b2[col]; g2v[ctl] = g2[col]; be2v[ctl] = be2[col];
    }
#pragma unroll
    for (int rb = 0; rb < 2; ++rb)
#pragma unroll
        for (int reg = 0; reg < 4; ++reg) {
            float s = 0.f, ss = 0.f;
#pragma unroll
            for (int ctl = 0; ctl < 4; ++ctl) {
                float x = acc2[rb][ctl][reg] + b2v[ctl];
                s += x; ss = fmaf(x, x, ss);
            }
#pragma unroll
            for (int m = 1; m <= 8; m <<= 1) {
                s += __shfl_xor(s, m, 64);
                ss += __shfl_xor(ss, m, 64);
            }
            if (li == 0) {
                lnred[w][rb * 16 + lg * 4 + reg][0] = s;
                lnred[w][rb * 16 + lg * 4 + reg][1] = ss;
            }
        }
    __syncthreads();  // B3
#pragma unroll
    for (int rb = 0; rb < 2; ++rb)
#pragma unroll
        for (int reg = 0; reg < 4; ++reg) {
            int row = rb * 16 + lg * 4 + reg;
            float s = lnred[0][row][0] + lnred[1][row][0] + lnred[2][row][0] + lnred[3][row][0];
            float ss = lnred[0][row][1] + lnred[1][row][1] + lnred[2][row][1] + lnred[3][row][1];
            float mean = s * (1.0f / 256.0f);
            float var = ss * (1.0f / 256.0f) - mean * mean;
            float rs = rsqrtf(var + 1e-5f);
#pragma unroll
            for (int ctl = 0; ctl < 4; ++ctl) {
                float x = acc2[rb][ctl][reg] + b2v[ctl];
                acc2[rb][ctl][reg] = (x - mean) * rs * g2v[ctl] + be2v[ctl];
            }
        }

    // ---------------- max-pool / emit --------------------------------------
    if (K == 16) {  // two centers per block
#pragma unroll
        for (int rb = 0; rb < 2; ++rb)
#pragma unroll
            for (int ctl = 0; ctl < 4; ++ctl) {
                float mx = -3.4e38f;
#pragma unroll
                for (int reg = 0; reg < 4; ++reg) mx = fmaxf(mx, acc2[rb][ctl][reg]);
                mx = fmaxf(mx, __shfl_xor(mx, 16, 64));
                mx = fmaxf(mx, __shfl_xor(mx, 32, 64));
                if (lg == 0)
                    outf[(size_t)(blockIdx.x * 2 + rb) * TOK + w * 64 + ctl * 16 + li] = mx;
            }
    } else {  // K==32: one center; K==64: partial row (combined in token_mfma)
#pragma unroll
        for (int ctl = 0; ctl < 4; ++ctl) {
            float mx = -3.4e38f;
#pragma unroll
            for (int rb = 0; rb < 2; ++rb)
#pragma unroll
                for (int reg = 0; reg < 4; ++reg) mx = fmaxf(mx, acc2[rb][ctl][reg]);
            mx = fmaxf(mx, __shfl_xor(mx, 16, 64));
            mx = fmaxf(mx, __shfl_xor(mx, 32, 64));
            if (lg == 0)
                outf[(size_t)blockIdx.x * TOK + w * 64 + ctl * 16 + li] = mx;
        }
    }
}

// ---------------- Token MLP via bf16x3 MFMA, tok_in built on the fly -------
// Each 32-col k-chunk lies entirely in one segment:
//  ks 0..3: pf[center]; 4..11: sf0; 12..19: sf1; 20..27: max(sf2p even,odd);
//  28..30: PE.
__global__ __launch_bounds__(256, 2) void token_mfma(
    const float* __restrict__ pf, const int* __restrict__ center_idx,
    const float* __restrict__ pc, const float* __restrict__ sf0,
    const float* __restrict__ sf1, const float* __restrict__ sf2p,
    const unsigned short* __restrict__ pk1, const float* __restrict__ b1,
    const float* __restrict__ g1, const float* __restrict__ be1,
    const unsigned short* __restrict__ pk2, const float* __restrict__ b2,
    const float* __restrict__ g2, const float* __restrict__ be2,
    float* __restrict__ out) {
    __shared__ unsigned int hpk[32][260];
    __shared__ float lnred[4][32][2];
    const int w = threadIdx.x >> 6, l = threadIdx.x & 63;
    const int lg = l >> 4, li = l & 15;
    const int ws4 = 4 * w;
    const int rowbase = blockIdx.x * 32;

    int rowg[2];
    const float* pfc[2];
    float pcx[2], pcy[2], pcz[2];
#pragma unroll
    for (int rb = 0; rb < 2; ++rb) {
        int row = rowbase + rb * 16 + li;
        rowg[rb] = row;
        int b = row >> 9;
        int cidx = center_idx[row];
        pfc[rb] = pf + ((size_t)b * NPTS + cidx) * STEM;
        pcx[rb] = pc[(size_t)row * 3 + 0];
        pcy[rb] = pc[(size_t)row * 3 + 1];
        pcz[rb] = pc[(size_t)row * 3 + 2];
    }

    f32x4 acc1[2][4];
#pragma unroll
    for (int rb = 0; rb < 2; ++rb)
#pragma unroll
        for (int ctl = 0; ctl < 4; ++ctl) acc1[rb][ctl] = (f32x4){0.f, 0.f, 0.f, 0.f};

#pragma unroll 2
    for (int ks = 0; ks < 31; ++ks) {
        s16x8 Bh[4], Bl[4];
#pragma unroll
        for (int ctl = 0; ctl < 4; ++ctl)
            loadB(pk1, (ws4 + ctl) * 31 + ks, l, Bh[ctl], Bl[ctl]);
        s16x8 Ah[2], Al[2];
#pragma unroll
        for (int rb = 0; rb < 2; ++rb) {
            float v[8];
            if (ks < 20) {
                const float* src;
                if (ks < 4)       src = pfc[rb] + ks * 32 + lg * 8;
                else if (ks < 12) src = sf0 + (size_t)rowg[rb] * TOK + (ks - 4) * 32 + lg * 8;
                else              src = sf1 + (size_t)rowg[rb] * TOK + (ks - 12) * 32 + lg * 8;
                float4 f0 = *(const float4*)src;
                float4 f1 = *(const float4*)(src + 4);
                v[0] = f0.x; v[1] = f0.y; v[2] = f0.z; v[3] = f0.w;
                v[4] = f1.x; v[5] = f1.y; v[6] = f1.z; v[7] = f1.w;
            } else if (ks < 28) {
                // sf2 = max of the two K=64 partial rows
                const float* sa = sf2p + ((size_t)rowg[rb] * 2) * TOK + (ks - 20) * 32 + lg * 8;
                const float* sb = sa + TOK;
                float4 a0 = *(const float4*)sa;
                float4 a1 = *(const float4*)(sa + 4);
                float4 b0 = *(const float4*)sb;
                float4 b1 = *(const float4*)(sb + 4);
                v[0] = fmaxf(a0.x, b0.x); v[1] = fmaxf(a0.y, b0.y);
                v[2] = fmaxf(a0.z, b0.z); v[3] = fmaxf(a0.w, b0.w);
                v[4] = fmaxf(a1.x, b1.x); v[5] = fmaxf(a1.y, b1.y);
                v[6] = fmaxf(a1.z, b1.z); v[7] = fmaxf(a1.w, b1.w);
            } else {
                float c = (ks == 28) ? pcx[rb] : ((ks == 29) ? pcy[rb] : pcz[rb]);
#pragma unroll
                for (int j = 0; j < 8; ++j) {
                    float fr = (lg & 1) ? FR15c[8 + j] : FR15c[j];
                    float ang = c * fr;
                    v[j] = (lg < 2) ? __sinf(ang) : __cosf(ang);
                }
            }
            bsplit8(v, Ah[rb], Al[rb]);
        }
#pragma unroll
        for (int ctl = 0; ctl < 4; ++ctl)
#pragma unroll
            for (int rb = 0; rb < 2; ++rb) {
                acc1[rb][ctl] = __builtin_amdgcn_mfma_f32_16x16x32_bf16(Ah[rb], Bh[ctl], acc1[rb][ctl], 0, 0, 0);
                acc1[rb][ctl] = __builtin_amdgcn_mfma_f32_16x16x32_bf16(Ah[rb], Bl[ctl], acc1[rb][ctl], 0, 0, 0);
                acc1[rb][ctl] = __builtin_amdgcn_mfma_f32_16x16x32_bf16(Al[rb], Bh[ctl], acc1[rb][ctl], 0, 0, 0);
            }
    }

    {
        float b1v[4], g1v[4], be1v[4];
#pragma unroll
        for (int ctl = 0; ctl < 4; ++ctl) {
            int col = w * 64 + ctl * 16 + li;
            b1v[ctl] = b1[col]; g1v[ctl] = g1[col]; be1v[ctl] = be1[col];
        }
#pragma unroll
        for (int rb = 0; rb < 2; ++rb)
#pragma unroll
            for (int reg = 0; reg < 4; ++reg) {
                float s = 0.f, ss = 0.f;
#pragma unroll
                for (int ctl = 0; ctl < 4; ++ctl) {
                    float x = acc1[rb][ctl][reg] + b1v[ctl];
                    s += x; ss = fmaf(x, x, ss);
                }
#pragma unroll
                for (int m = 1; m <= 8; m <<= 1) {
                    s += __shfl_xor(s, m, 64);
                    ss += __shfl_xor(ss, m, 64);
                }
                if (li == 0) {
                    lnred[w][rb * 16 + lg * 4 + reg][0] = s;
                    lnred[w][rb * 16 + lg * 4 + reg][1] = ss;
                }
            }
        __syncthreads();
#pragma unroll
        for (int rb = 0; rb < 2; ++rb)
#pragma unroll
            for (int reg = 0; reg < 4; ++reg) {
                int row = rb * 16 + lg * 4 + reg;
                float s = lnred[0][row][0] + lnred[1][row][0] + lnred[2][row][0] + lnred[3][row][0];
                float ss = lnred[0][row][1] + lnred[1][row][1] + lnred[2][row][1] + lnred[3][row][1];
                float mean = s * (1.0f / 256.0f);
                float var = ss * (1.0f / 256.0f) - mean * mean;
                float rs = rsqrtf(var + 1e-5f);
#pragma unroll
                for (int ctl = 0; ctl < 4; ++ctl) {
                    float x = acc1[rb][ctl][reg] + b1v[ctl];
                    acc1[rb][ctl][reg] = gelu_exact((x - mean) * rs * g1v[ctl] + be1v[ctl]);
                }
            }
    }

#pragma unroll
    for (int rb = 0; rb < 2; ++rb)
#pragma unroll
        for (int ctl = 0; ctl < 4; ++ctl) {
            unsigned w0, w1, w2, w3;
            pkpair(acc1[rb][ctl][0], acc1[rb][ctl][1], w0, w1);
            pkpair(acc1[rb][ctl][2], acc1[rb][ctl][3], w2, w3);
            int r0 = rb * 16 + lg * 4;
            int kc = w * 64 + ctl * 16 + li;
            hpk[r0 + 0][kc] = w0; hpk[r0 + 1][kc] = w1;
            hpk[r0 + 2][kc] = w2; hpk[r0 + 3][kc] = w3;
        }
    __syncthreads();

    f32x4 acc2[2][4];
#pragma unroll
    for (int rb = 0; rb < 2; ++rb)
#pragma unroll
        for (int ctl = 0; ctl < 4; ++ctl) acc2[rb][ctl] = (f32x4){0.f, 0.f, 0.f, 0.f};
#pragma unroll
    for (int q = 0; q < 8; ++q) {
        s16x8 Bh[4], Bl[4];
#pragma unroll
        for (int ctl = 0; ctl < 4; ++ctl)
            loadB(pk2, (ws4 + ctl) * 8 + q, l, Bh[ctl], Bl[ctl]);
#pragma unroll
        for (int rb = 0; rb < 2; ++rb) {
            const unsigned int* hp = &hpk[rb * 16 + li][q * 32 + lg * 8];
            int4 xa = *(const int4*)hp;
            int4 xb = *(const int4*)(hp + 4);
            unsigned x[8] = {(unsigned)xa.x, (unsigned)xa.y, (unsigned)xa.z, (unsigned)xa.w,
                             (unsigned)xb.x, (unsigned)xb.y, (unsigned)xb.z, (unsigned)xb.w};
            union { s16x8 s; unsigned w[4]; } H, L;
#pragma unroll
            for (int p = 0; p < 4; ++p) {
                H.w[p] = (x[2 * p] >> 16) | (x[2 * p + 1] & 0xffff0000u);
                L.w[p] = (x[2 * p] & 0xffffu) | (x[2 * p + 1] << 16);
            }
#pragma unroll
            for (int ctl = 0; ctl < 4; ++ctl) {
                acc2[rb][ctl] = __builtin_amdgcn_mfma_f32_16x16x32_bf16(H.s, Bh[ctl], acc2[rb][ctl], 0, 0, 0);
                acc2[rb][ctl] = __builtin_amdgcn_mfma_f32_16x16x32_bf16(H.s, Bl[ctl], acc2[rb][ctl], 0, 0, 0);
                acc2[rb][ctl] = __builtin_amdgcn_mfma_f32_16x16x32_bf16(L.s, Bh[ctl], acc2[rb][ctl], 0, 0, 0);
            }
        }
    }

    float b2v[4], g2v[4], be2v[4];
#pragma unroll
    for (int ctl = 0; ctl < 4; ++ctl) {
        int col = w * 64 + ctl * 16 + li;
        b2v[ctl] = b2[col]; g2v[ctl] = g2[col]; be2v[ctl] = be2[col];
    }
#pragma unroll
    for (int rb = 0; rb < 2; ++rb)
#pragma unroll
        for (int reg = 0; reg < 4; ++reg) {
            float s = 0.f, ss = 0.f;
#pragma unroll
            for (int ctl = 0; ctl < 4; ++ctl) {
                float x = acc2[rb][ctl][reg] + b2v[ctl];
                s += x; ss = fmaf(x, x, ss);
            }
#pragma unroll
            for (int m = 1; m <= 8; m <<= 1) {
                s += __shfl_xor(s, m, 64);
                ss += __shfl_xor(ss, m, 64);
            }
            if (li == 0) {
                lnred[w][rb * 16 + lg * 4 + reg][0] = s;
                lnred[w][rb * 16 + lg * 4 + reg][1] = ss;
            }
        }
    __syncthreads();
#pragma unroll
    for (int rb = 0; rb < 2; ++rb)
#pragma unroll
        for (int reg = 0; reg < 4; ++reg) {
            int row = rb * 16 + lg * 4 + reg;
            float s = lnred[0][row][0] + lnred[1][row][0] + lnred[2][row][0] + lnred[3][row][0];
            float ss = lnred[0][row][1] + lnred[1][row][1] + lnred[2][row][1] + lnred[3][row][1];
            float mean = s * (1.0f / 256.0f);
            float var = ss * (1.0f / 256.0f) - mean * mean;
            float rs = rsqrtf(var + 1e-5f);
#pragma unroll
            for (int ctl = 0; ctl < 4; ++ctl) {
                float x = acc2[rb][ctl][reg] + b2v[ctl];
                float v = (x - mean) * rs * g2v[ctl] + be2v[ctl];
                out[(size_t)(rowbase + row) * TOK + w * 64 + ctl * 16 + li] = v;
            }
        }
}

extern "C" void kernel_launch(void* const* d_in, const int* in_sizes, int n_in,
                              void* d_out, int out_size, void* d_ws, size_t ws_size,
                              hipStream_t stream) {
    const float* xyz  = (const float*)d_in[0];
    const float* pf   = (const float*)d_in[1];
    const float* sW1  = (const float*)d_in[2];
    const float* sb1  = (const float*)d_in[3];
    const float* sg1  = (const float*)d_in[4];
    const float* sbe1 = (const float*)d_in[5];
    const float* sW2  = (const float*)d_in[6];
    const float* sb2  = (const float*)d_in[7];
    const float* sg2  = (const float*)d_in[8];
    const float* sbe2 = (const float*)d_in[9];
    const float* tW1  = (const float*)d_in[10];
    const float* tb1  = (const float*)d_in[11];
    const float* tg1  = (const float*)d_in[12];
    const float* tbe1 = (const float*)d_in[13];
    const float* tW2  = (const float*)d_in[14];
    const float* tb2  = (const float*)d_in[15];
    const float* tg2  = (const float*)d_in[16];
    const float* tbe2 = (const float*)d_in[17];

    float* out_tok = (float*)d_out;
    float* out_pc  = out_tok + (size_t)BATCH * NCTR * TOK;

    char* ws = (char*)d_ws;
    int* center_idx = (int*)ws;   ws += (size_t)BATCH * NCTR * 4;
    float* pc_ws    = (float*)ws; ws += (size_t)BATCH * NCTR * 3 * 4;
    int* nbr0       = (int*)ws;   ws += (size_t)BATCH * NCTR * 16 * 4;
    int* nbr1       = (int*)ws;   ws += (size_t)BATCH * NCTR * 32 * 4;
    int* nbr2       = (int*)ws;   ws += (size_t)BATCH * NCTR * 64 * 4;
    float* sf0      = (float*)ws; ws += (size_t)BATCH * NCTR * TOK * 4;
    float* sf1      = (float*)ws; ws += (size_t)BATCH * NCTR * TOK * 4;
    float* sf2p     = (float*)ws; ws += (size_t)BATCH * NCTR * 2 * TOK * 4;  // K=64 partials
    const size_t PK1_S  = 16 * 5 * 64 * 16;    // ushorts per scale (sW1)
    const size_t PK2_S  = 16 * 8 * 64 * 16;    // ushorts per scale (sW2)
    const size_t PKT1_S = 16 * 31 * 64 * 16;   // ushorts (tW1)
    const size_t PKT2_S = 16 * 8 * 64 * 16;    // ushorts (tW2)
    unsigned short* pkW1 = (unsigned short*)ws; ws += 3 * PK1_S * 2;
    unsigned short* pkW2 = (unsigned short*)ws; ws += 3 * PK2_S * 2;
    unsigned short* pkT1 = (unsigned short*)ws; ws += PKT1_S * 2;
    unsigned short* pkT2 = (unsigned short*)ws; ws += PKT2_S * 2;

    {
        dim3 gp1((16 * 5 * 64 + 255) / 256, 3);
        pack_w<<<gp1, 256, 0, stream>>>(sW1, pkW1, D_IN, 5);
        dim3 gp2((16 * 8 * 64 + 255) / 256, 3);
        pack_w<<<gp2, 256, 0, stream>>>(sW2, pkW2, TOK, 8);
        dim3 gpt1((16 * 31 * 64 + 255) / 256, 1);
        pack_w<<<gpt1, 256, 0, stream>>>(tW1, pkT1, D_TOK, 31);
        dim3 gpt2((16 * 8 * 64 + 255) / 256, 1);
        pack_w<<<gpt2, 256, 0, stream>>>(tW2, pkT2, TOK, 8);
    }

    fps_kernel<<<BATCH, 256, 0, stream>>>(xyz, center_idx, pc_ws, out_pc);

    ballq_kernel<16><<<BATCH * NCTR / 4, 256, 0, stream>>>(xyz, pc_ws, nbr0, (float)(0.1 * 0.1));
    ballq_kernel<32><<<BATCH * NCTR / 4, 256, 0, stream>>>(xyz, pc_ws, nbr1, (float)(0.2 * 0.2));
    ballq_kernel<64><<<BATCH * NCTR / 4, 256, 0, stream>>>(xyz, pc_ws, nbr2, (float)(0.4 * 0.4));

    // 32 rows per block
    scale_mfma<16><<<(BATCH * NCTR * 16) / 32, 256, 0, stream>>>(
        xyz, pf, pkW1 + 0 * PK1_S, sb1 + 0 * TOK, sg1 + 0 * TOK, sbe1 + 0 * TOK,
        pkW2 + 0 * PK2_S, sb2 + 0 * TOK, sg2 + 0 * TOK, sbe2 + 0 * TOK,
        nbr0, pc_ws, sf0);
    scale_mfma<32><<<(BATCH * NCTR * 32) / 32, 256, 0, stream>>>(
        xyz, pf, pkW1 + 1 * PK1_S, sb1 + 1 * TOK, sg1 + 1 * TOK, sbe1 + 1 * TOK,
        pkW2 + 1 * PK2_S, sb2 + 1 * TOK, sg2 + 1 * TOK, sbe2 + 1 * TOK,
        nbr1, pc_ws, sf1);
    scale_mfma<64><<<(BATCH * NCTR * 64) / 32, 256, 0, stream>>>(
        xyz, pf, pkW1 + 2 * PK1_S, sb1 + 2 * TOK, sg1 + 2 * TOK, sbe1 + 2 * TOK,
        pkW2 + 2 * PK2_S, sb2 + 2 * TOK, sg2 + 2 * TOK, sbe2 + 2 * TOK,
        nbr2, pc_ws, sf2p);

    token_mfma<<<(BATCH * NCTR) / 32, 256, 0, stream>>>(
        pf, center_idx, pc_ws, sf0, sf1, sf2p,
        pkT1, tb1, tg1, tbe1, pkT2, tb2, tg2, tbe2, out_tok);
}

// Round 12
// 1373.440 us; speedup vs baseline: 1.2567x; 1.0710x over previous
//
#include <hip/hip_runtime.h>
#include <math.h>

#define BATCH 16
#define NPTS  4096
#define NCTR  512
#define STEM  128
#define TOK   256
#define D_IN  155   // 128 + 3 + 24
#define D_TOK 992   // 128 + 3*256 + 96

typedef short s16x8 __attribute__((ext_vector_type(8)));
typedef float f32x4 __attribute__((ext_vector_type(4)));

// 10000^(-i/15), i=0..15 (token-PE frequencies)
static constexpr float FR15c[16] = {
    1.0f, 0.5411695265464638f, 0.2928644487857941f, 0.15848931670188904f,
    0.08576958626508713f, 0.04641588851809502f, 0.02511886507272720f, 0.01359356392547488f,
    0.007356422487646341f, 0.003981071710586548f, 0.002154434798285365f, 0.001165914465673268f,
    0.0006309573450125754f, 0.0003414548910222948f, 0.0001847849769866168f, 0.0001f};

__device__ __forceinline__ unsigned short f2bf(float f) {
    unsigned u = __float_as_uint(f);
    u += 0x7FFF + ((u >> 16) & 1);
    return (unsigned short)(u >> 16);
}
__device__ __forceinline__ float bf2f(unsigned short b) {
    return __uint_as_float(((unsigned)b) << 16);
}

// split 8 f32 -> hi/lo bf16 fragments via v_cvt_pk_bf16_f32 (RNE)
__device__ __forceinline__ void bsplit8(const float* v, s16x8& hi, s16x8& lo) {
    union { s16x8 s; unsigned w[4]; } H, L;
#pragma unroll
    for (int p = 0; p < 4; ++p) {
        unsigned hp, lp;
        asm("v_cvt_pk_bf16_f32 %0, %1, %2" : "=v"(hp) : "v"(v[2 * p]), "v"(v[2 * p + 1]));
        float r0 = v[2 * p]     - __uint_as_float(hp << 16);
        float r1 = v[2 * p + 1] - __uint_as_float(hp & 0xffff0000u);
        asm("v_cvt_pk_bf16_f32 %0, %1, %2" : "=v"(lp) : "v"(r0), "v"(r1));
        H.w[p] = hp; L.w[p] = lp;
    }
    hi = H.s; lo = L.s;
}

// pack two f32 into two (hi16|lo16) u32 words
__device__ __forceinline__ void pkpair(float v0, float v1, unsigned& w0, unsigned& w1) {
    unsigned hp, lp;
    asm("v_cvt_pk_bf16_f32 %0, %1, %2" : "=v"(hp) : "v"(v0), "v"(v1));
    float r0 = v0 - __uint_as_float(hp << 16);
    float r1 = v1 - __uint_as_float(hp & 0xffff0000u);
    asm("v_cvt_pk_bf16_f32 %0, %1, %2" : "=v"(lp) : "v"(r0), "v"(r1));
    w0 = (hp << 16) | (lp & 0xffffu);
    w1 = (hp & 0xffff0000u) | (lp >> 16);
}

// B-fragment direct load: global (L2-hot) -> VGPR, 16B hi + 16B lo per lane
__device__ __forceinline__ void loadB(const unsigned short* __restrict__ pk,
                                      int frag, int l, s16x8& bh, s16x8& bl) {
    const unsigned short* p = pk + (size_t)frag * 1024 + (size_t)l * 8;
    bh = *(const s16x8*)p;
    bl = *(const s16x8*)(p + 512);
}

// fast exact-GELU: A&S 7.1.26 erf (|abs err| < 2e-7)
__device__ __forceinline__ float gelu_exact(float x) {
    float z = x * 0.70710678118654752f;
    float a = fabsf(z);
    float t = __builtin_amdgcn_rcpf(fmaf(0.3275911f, a, 1.0f));
    float p = fmaf(1.061405429f, t, -1.453152027f);
    p = fmaf(p, t, 1.421413741f);
    p = fmaf(p, t, -0.284496736f);
    p = fmaf(p, t, 0.254829592f);
    p = p * t;
    float e = __expf(-z * z);
    float y = fmaf(-p, e, 1.0f);
    y = (z < 0.0f) ? -y : y;
    return 0.5f * x * (1.0f + y);
}

// exact, non-contracted squared distance to match numpy f32 rounding
__device__ __forceinline__ float sq3(float ax, float ay, float az,
                                     float bx, float by, float bz) {
    float dx = __fsub_rn(ax, bx);
    float dy = __fsub_rn(ay, by);
    float dz = __fsub_rn(az, bz);
    float d = __fmul_rn(dx, dx);
    d = __fadd_rn(d, __fmul_rn(dy, dy));
    d = __fadd_rn(d, __fmul_rn(dz, dz));
    return d;
}

// argmax-combine one DPP row_ror step (total-order max: rotation-valid)
template <int CTRL>
__device__ __forceinline__ void dpp_amax(float& bv, int& bi) {
    int vv = __builtin_amdgcn_update_dpp(__float_as_int(bv), __float_as_int(bv),
                                         CTRL, 0xF, 0xF, false);
    int oi = __builtin_amdgcn_update_dpp(bi, bi, CTRL, 0xF, 0xF, false);
    float ov = __int_as_float(vv);
    if (ov > bv || (ov == bv && oi < bi)) { bv = ov; bi = oi; }
}
__device__ __forceinline__ void row_amax16(float& bv, int& bi) {
    dpp_amax<0x128>(bv, bi);   // row_ror:8
    dpp_amax<0x124>(bv, bi);   // row_ror:4
    dpp_amax<0x122>(bv, bi);   // row_ror:2
    dpp_amax<0x121>(bv, bi);   // row_ror:1
}

// sum-reduce over the 16-lane row via DPP row_ror (register-lane, no LDS pipe;
// rotation is exact for commutative f32 add up to per-lane rounding order —
// only lane li==0's value is consumed).
template <int CTRL>
__device__ __forceinline__ float dpp_fadd(float x) {
    int r = __builtin_amdgcn_update_dpp(0, __float_as_int(x), CTRL, 0xF, 0xF, true);
    return x + __int_as_float(r);
}
__device__ __forceinline__ void row_sum16x2(float& s, float& ss) {
    s = dpp_fadd<0x128>(s);  ss = dpp_fadd<0x128>(ss);
    s = dpp_fadd<0x124>(s);  ss = dpp_fadd<0x124>(ss);
    s = dpp_fadd<0x122>(s);  ss = dpp_fadd<0x122>(ss);
    s = dpp_fadd<0x121>(s);  ss = dpp_fadd<0x121>(ss);
}

// ---------------- FPS: 256 threads, DPP row-reduce, 1 barrier/step ---------
__global__ __launch_bounds__(256) void fps_kernel(const float* __restrict__ xyz,
                                                  int* __restrict__ center_idx,
                                                  float* __restrict__ pc_ws,
                                                  float* __restrict__ pc_out) {
    int b = blockIdx.x;
    int t = threadIdx.x;
    const int w = t >> 6, lane = t & 63;
    const float* X = xyz + (size_t)b * NPTS * 3;
    __shared__ __align__(16) float sxyz[NPTS * 3];  // 48 KB
    __shared__ float swv[2][16];
    __shared__ int   swi[2][16];
    __shared__ int   hist[NCTR];                    // 2 KB
    {
        const float4* src = (const float4*)X;
        float4* dst = (float4*)sxyz;
        for (int i = t; i < NPTS * 3 / 4; i += 256) dst[i] = src[i];
    }
    __syncthreads();
    float px[16], py[16], pz[16], dist[16];
#pragma unroll
    for (int j = 0; j < 16; ++j) {
        int i = t + 256 * j;
        px[j] = sxyz[i * 3 + 0];
        py[j] = sxyz[i * 3 + 1];
        pz[j] = sxyz[i * 3 + 2];
        dist[j] = 1e10f;
    }
    int far = 0;
    for (int s = 0; s < NCTR; ++s) {
        if (t == 0) hist[s] = far;
        float cx = sxyz[far * 3 + 0];
        float cy = sxyz[far * 3 + 1];
        float cz = sxyz[far * 3 + 2];
        float bv = -1.0f;
        int bi = 0;
#pragma unroll
        for (int j = 0; j < 16; ++j) {
            float d = sq3(px[j], py[j], pz[j], cx, cy, cz);
            float nd = fminf(dist[j], d);
            dist[j] = nd;
            if (nd > bv) { bv = nd; bi = t + 256 * j; }  // strict >: earliest idx
        }
        row_amax16(bv, bi);
        const int p = s & 1;
        if ((lane & 15) == 0) {
            int r = w * 4 + (lane >> 4);
            swv[p][r] = bv; swi[p][r] = bi;
        }
        __syncthreads();
        bv = swv[p][lane & 15];
        bi = swi[p][lane & 15];
        row_amax16(bv, bi);
        far = bi;
    }
    __syncthreads();
    for (int s = t; s < NCTR; s += 256) {
        int idx = hist[s];
        center_idx[b * NCTR + s] = idx;
        float cx = sxyz[idx * 3], cy = sxyz[idx * 3 + 1], cz = sxyz[idx * 3 + 2];
        size_t po = (size_t)(b * NCTR + s) * 3;
        pc_ws[po] = cx; pc_ws[po + 1] = cy; pc_ws[po + 2] = cz;
        pc_out[po] = cx; pc_out[po + 1] = cy; pc_out[po + 2] = cz;
    }
}

// ---------------- Ball query (unchanged) ----------------------------------
template <int K>
__global__ __launch_bounds__(256) void ballq_kernel(const float* __restrict__ xyz,
                                                    const float* __restrict__ pc,
                                                    int* __restrict__ nbr,
                                                    float rr) {
    int cid = blockIdx.x * 4 + (threadIdx.x >> 6);
    int lane = threadIdx.x & 63;
    int b = cid >> 9;
    const float* X = xyz + (size_t)b * NPTS * 3;
    float cx = pc[(size_t)cid * 3 + 0];
    float cy = pc[(size_t)cid * 3 + 1];
    float cz = pc[(size_t)cid * 3 + 2];
    int cnt = 0, first = 0;
    bool have_first = false;
    long long base = (long long)cid * K;
    for (int it = 0; it < NPTS / 64; ++it) {
        int i = it * 64 + lane;
        float d = sq3(cx, cy, cz, X[i * 3], X[i * 3 + 1], X[i * 3 + 2]);
        bool ok = d <= rr;
        unsigned long long mask = __ballot(ok);
        if (!have_first && mask) {
            first = it * 64 + (int)__builtin_ctzll(mask);
            have_first = true;
        }
        int pos = cnt + (int)__popcll(mask & ((1ull << lane) - 1ull));
        if (ok && pos < K) nbr[base + pos] = i;
        cnt += (int)__popcll(mask);
        if (cnt >= K) break;
    }
    int fill = cnt < K ? cnt : K;
    for (int j = fill + lane; j < K; j += 64) nbr[base + j] = first;
}

// ---------------- Weight pack: hi-plane/lo-plane bf16 MFMA B-frags --------
__global__ __launch_bounds__(256) void pack_w(const float* __restrict__ Wbase,
                                              unsigned short* __restrict__ out,
                                              int Kdim, int KS) {
    int s = blockIdx.y;
    const float* W = Wbase + (size_t)s * Kdim * TOK;
    unsigned short* o = out + (size_t)s * 16 * KS * 64 * 16;
    int tid = blockIdx.x * 256 + threadIdx.x;
    if (tid >= 16 * KS * 64) return;
    int lane = tid & 63;
    int frag = tid >> 6;
    int ks = frag % KS;
    int ct = frag / KS;
    int col = ct * 16 + (lane & 15);
    int k0 = ks * 32 + (lane >> 4) * 8;
    unsigned short* hi = o + (size_t)frag * 1024 + lane * 8;
    unsigned short* lo = hi + 512;
#pragma unroll
    for (int j = 0; j < 8; ++j) {
        int k = k0 + j;
        float v = (k < Kdim) ? W[(size_t)k * TOK + col] : 0.0f;
        unsigned short h = f2bf(v);
        hi[j] = h;
        lo[j] = f2bf(v - bf2f(h));
    }
}

// unpack 8 hi|lo u32 words -> Ah/Al fragments via v_perm_b32 (1 op per word)
__device__ __forceinline__ void unpackHL(const unsigned* x, s16x8& Ah, s16x8& Al) {
    union { s16x8 s; unsigned w[4]; } H, L;
#pragma unroll
    for (int p = 0; p < 4; ++p) {
        H.w[p] = __builtin_amdgcn_perm(x[2 * p + 1], x[2 * p], 0x07060302u);
        L.w[p] = __builtin_amdgcn_perm(x[2 * p + 1], x[2 * p], 0x05040100u);
    }
    Ah = H.s; Al = L.s;
}

// ---------------- Per-scale grouped MLP via bf16x3 MFMA --------------------
// 32-row blocks, ONE-PASS skeleton (proven round-9/11 structure).
// K=64 centers span two blocks: each block emits a PARTIAL max row to
// sf2p[2*c+half]; token_mfma combines with fmaxf.
template <int K>
__global__ __launch_bounds__(256, 2) void scale_mfma(
    const float* __restrict__ xyz, const float* __restrict__ pf,
    const unsigned short* __restrict__ pk1, const float* __restrict__ b1,
    const float* __restrict__ g1, const float* __restrict__ be1,
    const unsigned short* __restrict__ pk2, const float* __restrict__ b2,
    const float* __restrict__ g2, const float* __restrict__ be2,
    const int* __restrict__ nbr, const float* __restrict__ pc,
    float* __restrict__ outf) {
    __shared__ unsigned int hpk[32][260];   // 33 KB packed-bf16 h (32 rows)
    __shared__ float lnred[4][32][2];       // 1 KB
    const int w = threadIdx.x >> 6, l = threadIdx.x & 63;
    const int lg = l >> 4, li = l & 15;
    const int ws4 = 4 * w;

    int nb[2];
    float relx[2], rely[2], relz[2];
#pragma unroll
    for (int rb = 0; rb < 2; ++rb) {
        int row_g = blockIdx.x * 32 + rb * 16 + li;
        int c = (blockIdx.x * 32 + rb * 16) / K;   // li never crosses a center
        int b = c >> 9;
        int n = nbr[row_g];
        nb[rb] = b * NPTS + n;
        const float* X = xyz + (size_t)nb[rb] * 3;
        const float* C = pc + (size_t)c * 3;
        relx[rb] = __fsub_rn(X[0], C[0]);
        rely[rb] = __fsub_rn(X[1], C[1]);
        relz[rb] = __fsub_rn(X[2], C[2]);
    }

    // ---------------- MLP1: [32 x 160] @ [160 x 64-slice] (bf16x3) --------
    f32x4 acc1[2][4];
#pragma unroll
    for (int rb = 0; rb < 2; ++rb)
#pragma unroll
        for (int ctl = 0; ctl < 4; ++ctl) acc1[rb][ctl] = (f32x4){0.f, 0.f, 0.f, 0.f};

#pragma unroll
    for (int ks = 0; ks < 5; ++ks) {
        s16x8 Bh[4], Bl[4];
#pragma unroll
        for (int ctl = 0; ctl < 4; ++ctl)
            loadB(pk1, (ws4 + ctl) * 5 + ks, l, Bh[ctl], Bl[ctl]);
        s16x8 Ah[2], Al[2];
#pragma unroll
        for (int rb = 0; rb < 2; ++rb) {
            float v[8];
            if (ks < 4) {
                const float* src = pf + (size_t)nb[rb] * STEM + ks * 32 + lg * 8;
                float4 f0 = *(const float4*)src;
                float4 f1 = *(const float4*)(src + 4);
                v[0] = f0.x; v[1] = f0.y; v[2] = f0.z; v[3] = f0.w;
                v[4] = f1.x; v[5] = f1.y; v[6] = f1.z; v[7] = f1.w;
            } else {
#pragma unroll
                for (int j = 0; j < 8; ++j) {
                    int ch = lg * 8 + j;
                    float val = 0.0f;
                    if (ch < 3) {
                        val = (ch == 0) ? relx[rb] : ((ch == 1) ? rely[rb] : relz[rb]);
                    } else if (ch < 27) {
                        int rem = ch - 3;
                        int axis = rem >> 3, r8 = rem & 7;
                        int fi = (r8 < 4) ? r8 : r8 - 4;
                        float fr = (fi == 0) ? 1.0f
                                  : (fi == 1) ? 0.046415888336127795f
                                  : (fi == 2) ? 0.0021544346900318843f : 1e-4f;
                        float rl = (axis == 0) ? relx[rb] : ((axis == 1) ? rely[rb] : relz[rb]);
                        float ang = rl * fr;
                        val = (r8 < 4) ? __sinf(ang) : __cosf(ang);
                    }
                    v[j] = val;
                }
            }
            bsplit8(v, Ah[rb], Al[rb]);
        }
#pragma unroll
        for (int ctl = 0; ctl < 4; ++ctl)
#pragma unroll
            for (int rb = 0; rb < 2; ++rb) {
                acc1[rb][ctl] = __builtin_amdgcn_mfma_f32_16x16x32_bf16(Ah[rb], Bh[ctl], acc1[rb][ctl], 0, 0, 0);
                acc1[rb][ctl] = __builtin_amdgcn_mfma_f32_16x16x32_bf16(Ah[rb], Bl[ctl], acc1[rb][ctl], 0, 0, 0);
                acc1[rb][ctl] = __builtin_amdgcn_mfma_f32_16x16x32_bf16(Al[rb], Bh[ctl], acc1[rb][ctl], 0, 0, 0);
            }
    }

    // ---------------- bias + LN1 (DPP row-sum + cross-wave) + GELU ---------
    {
        float b1v[4], g1v[4], be1v[4];
#pragma unroll
        for (int ctl = 0; ctl < 4; ++ctl) {
            int col = w * 64 + ctl * 16 + li;
            b1v[ctl] = b1[col]; g1v[ctl] = g1[col]; be1v[ctl] = be1[col];
        }
#pragma unroll
        for (int rb = 0; rb < 2; ++rb)
#pragma unroll
            for (int reg = 0; reg < 4; ++reg) {
                float s = 0.f, ss = 0.f;
#pragma unroll
                for (int ctl = 0; ctl < 4; ++ctl) {
                    float x = acc1[rb][ctl][reg] + b1v[ctl];
                    s += x; ss = fmaf(x, x, ss);
                }
                row_sum16x2(s, ss);
                if (li == 0) {
                    lnred[w][rb * 16 + lg * 4 + reg][0] = s;
                    lnred[w][rb * 16 + lg * 4 + reg][1] = ss;
                }
            }
        __syncthreads();  // B1
#pragma unroll
        for (int rb = 0; rb < 2; ++rb)
#pragma unroll
            for (int reg = 0; reg < 4; ++reg) {
                int row = rb * 16 + lg * 4 + reg;
                float s = lnred[0][row][0] + lnred[1][row][0] + lnred[2][row][0] + lnred[3][row][0];
                float ss = lnred[0][row][1] + lnred[1][row][1] + lnred[2][row][1] + lnred[3][row][1];
                float mean = s * (1.0f / 256.0f);
                float var = ss * (1.0f / 256.0f) - mean * mean;
                float rs = rsqrtf(var + 1e-5f);
#pragma unroll
                for (int ctl = 0; ctl < 4; ++ctl) {
                    float x = acc1[rb][ctl][reg] + b1v[ctl];
                    acc1[rb][ctl][reg] = gelu_exact((x - mean) * rs * g1v[ctl] + be1v[ctl]);
                }
            }
    }

    // ---------------- park FULL h (packed hi|lo u32); acc1 dies here -------
#pragma unroll
    for (int rb = 0; rb < 2; ++rb)
#pragma unroll
        for (int ctl = 0; ctl < 4; ++ctl) {
            unsigned w0, w1, w2, w3;
            pkpair(acc1[rb][ctl][0], acc1[rb][ctl][1], w0, w1);
            pkpair(acc1[rb][ctl][2], acc1[rb][ctl][3], w2, w3);
            int r0 = rb * 16 + lg * 4;
            int kc = w * 64 + ctl * 16 + li;
            hpk[r0 + 0][kc] = w0; hpk[r0 + 1][kc] = w1;
            hpk[r0 + 2][kc] = w2; hpk[r0 + 3][kc] = w3;
        }
    __syncthreads();  // B2

    // ---------------- MLP2: [32 x 256] @ [256 x 64-slice] (bf16x3) ---------
    f32x4 acc2[2][4];
#pragma unroll
    for (int rb = 0; rb < 2; ++rb)
#pragma unroll
        for (int ctl = 0; ctl < 4; ++ctl) acc2[rb][ctl] = (f32x4){0.f, 0.f, 0.f, 0.f};

#pragma unroll
    for (int q = 0; q < 8; ++q) {
        s16x8 Bh[4], Bl[4];
#pragma unroll
        for (int ctl = 0; ctl < 4; ++ctl)
            loadB(pk2, (ws4 + ctl) * 8 + q, l, Bh[ctl], Bl[ctl]);
#pragma unroll
        for (int rb = 0; rb < 2; ++rb) {
            const unsigned int* hp = &hpk[rb * 16 + li][q * 32 + lg * 8];
            int4 xa = *(const int4*)hp;
            int4 xb = *(const int4*)(hp + 4);
            unsigned x[8] = {(unsigned)xa.x, (unsigned)xa.y, (unsigned)xa.z, (unsigned)xa.w,
                             (unsigned)xb.x, (unsigned)xb.y, (unsigned)xb.z, (unsigned)xb.w};
            s16x8 Ah2, Al2;
            unpackHL(x, Ah2, Al2);
#pragma unroll
            for (int ctl = 0; ctl < 4; ++ctl) {
                acc2[rb][ctl] = __builtin_amdgcn_mfma_f32_16x16x32_bf16(Ah2, Bh[ctl], acc2[rb][ctl], 0, 0, 0);
                acc2[rb][ctl] = __builtin_amdgcn_mfma_f32_16x16x32_bf16(Ah2, Bl[ctl], acc2[rb][ctl], 0, 0, 0);
                acc2[rb][ctl] = __builtin_amdgcn_mfma_f32_16x16x32_bf16(Al2, Bh[ctl], acc2[rb][ctl], 0, 0, 0);
            }
        }
    }

    // ---------------- bias + LN2 (DPP row-sum + cross-wave) ----------------
    float b2v[4], g2v[4], be2v[4];
#pragma unroll
    for (int ctl = 0; ctl < 4; ++ctl) {
        int col = w * 64 + ctl * 16 + li;
        b2v[ctl] = b2[col]; g2v[ctl] = g2[col]; be2v[ctl] = be2[col];
    }
#pragma unroll
    for (int rb = 0; rb < 2; ++rb)
#pragma unroll
        for (int reg = 0; reg < 4; ++reg) {
            float s = 0.f, ss = 0.f;
#pragma unroll
            for (int ctl = 0; ctl < 4; ++ctl) {
                float x = acc2[rb][ctl][reg] + b2v[ctl];
                s += x; ss = fmaf(x, x, ss);
            }
            row_sum16x2(s, ss);
            if (li == 0) {
                lnred[w][rb * 16 + lg * 4 + reg][0] = s;
                lnred[w][rb * 16 + lg * 4 + reg][1] = ss;
            }
        }
    __syncthreads();  // B3
#pragma unroll
    for (int rb = 0; rb < 2; ++rb)
#pragma unroll
        for (int reg = 0; reg < 4; ++reg) {
            int row = rb * 16 + lg * 4 + reg;
            float s = lnred[0][row][0] + lnred[1][row][0] + lnred[2][row][0] + lnred[3][row][0];
            float ss = lnred[0][row][1] + lnred[1][row][1] + lnred[2][row][1] + lnred[3][row][1];
            float mean = s * (1.0f / 256.0f);
            float var = ss * (1.0f / 256.0f) - mean * mean;
            float rs = rsqrtf(var + 1e-5f);
#pragma unroll
            for (int ctl = 0; ctl < 4; ++ctl) {
                float x = acc2[rb][ctl][reg] + b2v[ctl];
                acc2[rb][ctl][reg] = (x - mean) * rs * g2v[ctl] + be2v[ctl];
            }
        }

    // ---------------- max-pool / emit --------------------------------------
    if (K == 16) {  // two centers per block
#pragma unroll
        for (int rb = 0; rb < 2; ++rb)
#pragma unroll
            for (int ctl = 0; ctl < 4; ++ctl) {
                float mx = -3.4e38f;
#pragma unroll
                for (int reg = 0; reg < 4; ++reg) mx = fmaxf(mx, acc2[rb][ctl][reg]);
                mx = fmaxf(mx, __shfl_xor(mx, 16, 64));
                mx = fmaxf(mx, __shfl_xor(mx, 32, 64));
                if (lg == 0)
                    outf[(size_t)(blockIdx.x * 2 + rb) * TOK + w * 64 + ctl * 16 + li] = mx;
            }
    } else {  // K==32: one center; K==64: partial row (combined in token_mfma)
#pragma unroll
        for (int ctl = 0; ctl < 4; ++ctl) {
            float mx = -3.4e38f;
#pragma unroll
            for (int rb = 0; rb < 2; ++rb)
#pragma unroll
                for (int reg = 0; reg < 4; ++reg) mx = fmaxf(mx, acc2[rb][ctl][reg]);
            mx = fmaxf(mx, __shfl_xor(mx, 16, 64));
            mx = fmaxf(mx, __shfl_xor(mx, 32, 64));
            if (lg == 0)
                outf[(size_t)blockIdx.x * TOK + w * 64 + ctl * 16 + li] = mx;
        }
    }
}

// ---------------- Token MLP via bf16x3 MFMA, tok_in built on the fly -------
__global__ __launch_bounds__(256, 2) void token_mfma(
    const float* __restrict__ pf, const int* __restrict__ center_idx,
    const float* __restrict__ pc, const float* __restrict__ sf0,
    const float* __restrict__ sf1, const float* __restrict__ sf2p,
    const unsigned short* __restrict__ pk1, const float* __restrict__ b1,
    const float* __restrict__ g1, const float* __restrict__ be1,
    const unsigned short* __restrict__ pk2, const float* __restrict__ b2,
    const float* __restrict__ g2, const float* __restrict__ be2,
    float* __restrict__ out) {
    __shared__ unsigned int hpk[32][260];
    __shared__ float lnred[4][32][2];
    const int w = threadIdx.x >> 6, l = threadIdx.x & 63;
    const int lg = l >> 4, li = l & 15;
    const int ws4 = 4 * w;
    const int rowbase = blockIdx.x * 32;

    int rowg[2];
    const float* pfc[2];
    float pcx[2], pcy[2], pcz[2];
#pragma unroll
    for (int rb = 0; rb < 2; ++rb) {
        int row = rowbase + rb * 16 + li;
        rowg[rb] = row;
        int b = row >> 9;
        int cidx = center_idx[row];
        pfc[rb] = pf + ((size_t)b * NPTS + cidx) * STEM;
        pcx[rb] = pc[(size_t)row * 3 + 0];
        pcy[rb] = pc[(size_t)row * 3 + 1];
        pcz[rb] = pc[(size_t)row * 3 + 2];
    }

    f32x4 acc1[2][4];
#pragma unroll
    for (int rb = 0; rb < 2; ++rb)
#pragma unroll
        for (int ctl = 0; ctl < 4; ++ctl) acc1[rb][ctl] = (f32x4){0.f, 0.f, 0.f, 0.f};

#pragma unroll 2
    for (int ks = 0; ks < 31; ++ks) {
        s16x8 Bh[4], Bl[4];
#pragma unroll
        for (int ctl = 0; ctl < 4; ++ctl)
            loadB(pk1, (ws4 + ctl) * 31 + ks, l, Bh[ctl], Bl[ctl]);
        s16x8 Ah[2], Al[2];
#pragma unroll
        for (int rb = 0; rb < 2; ++rb) {
            float v[8];
            if (ks < 20) {
                const float* src;
                if (ks < 4)       src = pfc[rb] + ks * 32 + lg * 8;
                else if (ks < 12) src = sf0 + (size_t)rowg[rb] * TOK + (ks - 4) * 32 + lg * 8;
                else              src = sf1 + (size_t)rowg[rb] * TOK + (ks - 12) * 32 + lg * 8;
                float4 f0 = *(const float4*)src;
                float4 f1 = *(const float4*)(src + 4);
                v[0] = f0.x; v[1] = f0.y; v[2] = f0.z; v[3] = f0.w;
                v[4] = f1.x; v[5] = f1.y; v[6] = f1.z; v[7] = f1.w;
            } else if (ks < 28) {
                // sf2 = max of the two K=64 partial rows
                const float* sa = sf2p + ((size_t)rowg[rb] * 2) * TOK + (ks - 20) * 32 + lg * 8;
                const float* sb = sa + TOK;
                float4 a0 = *(const float4*)sa;
                float4 a1 = *(const float4*)(sa + 4);
                float4 b0 = *(const float4*)sb;
                float4 b1 = *(const float4*)(sb + 4);
                v[0] = fmaxf(a0.x, b0.x); v[1] = fmaxf(a0.y, b0.y);
                v[2] = fmaxf(a0.z, b0.z); v[3] = fmaxf(a0.w, b0.w);
                v[4] = fmaxf(a1.x, b1.x); v[5] = fmaxf(a1.y, b1.y);
                v[6] = fmaxf(a1.z, b1.z); v[7] = fmaxf(a1.w, b1.w);
            } else {
                float c = (ks == 28) ? pcx[rb] : ((ks == 29) ? pcy[rb] : pcz[rb]);
#pragma unroll
                for (int j = 0; j < 8; ++j) {
                    float fr = (lg & 1) ? FR15c[8 + j] : FR15c[j];
                    float ang = c * fr;
                    v[j] = (lg < 2) ? __sinf(ang) : __cosf(ang);
                }
            }
            bsplit8(v, Ah[rb], Al[rb]);
        }
#pragma unroll
        for (int ctl = 0; ctl < 4; ++ctl)
#pragma unroll
            for (int rb = 0; rb < 2; ++rb) {
                acc1[rb][ctl] = __builtin_amdgcn_mfma_f32_16x16x32_bf16(Ah[rb], Bh[ctl], acc1[rb][ctl], 0, 0, 0);
                acc1[rb][ctl] = __builtin_amdgcn_mfma_f32_16x16x32_bf16(Ah[rb], Bl[ctl], acc1[rb][ctl], 0, 0, 0);
                acc1[rb][ctl] = __builtin_amdgcn_mfma_f32_16x16x32_bf16(Al[rb], Bh[ctl], acc1[rb][ctl], 0, 0, 0);
            }
    }

    {
        float b1v[4], g1v[4], be1v[4];
#pragma unroll
        for (int ctl = 0; ctl < 4; ++ctl) {
            int col = w * 64 + ctl * 16 + li;
            b1v[ctl] = b1[col]; g1v[ctl] = g1[col]; be1v[ctl] = be1[col];
        }
#pragma unroll
        for (int rb = 0; rb < 2; ++rb)
#pragma unroll
            for (int reg = 0; reg < 4; ++reg) {
                float s = 0.f, ss = 0.f;
#pragma unroll
                for (int ctl = 0; ctl < 4; ++ctl) {
                    float x = acc1[rb][ctl][reg] + b1v[ctl];
                    s += x; ss = fmaf(x, x, ss);
                }
                row_sum16x2(s, ss);
                if (li == 0) {
                    lnred[w][rb * 16 + lg * 4 + reg][0] = s;
                    lnred[w][rb * 16 + lg * 4 + reg][1] = ss;
                }
            }
        __syncthreads();
#pragma unroll
        for (int rb = 0; rb < 2; ++rb)
#pragma unroll
            for (int reg = 0; reg < 4; ++reg) {
                int row = rb * 16 + lg * 4 + reg;
                float s = lnred[0][row][0] + lnred[1][row][0] + lnred[2][row][0] + lnred[3][row][0];
                float ss = lnred[0][row][1] + lnred[1][row][1] + lnred[2][row][1] + lnred[3][row][1];
                float mean = s * (1.0f / 256.0f);
                float var = ss * (1.0f / 256.0f) - mean * mean;
                float rs = rsqrtf(var + 1e-5f);
#pragma unroll
                for (int ctl = 0; ctl < 4; ++ctl) {
                    float x = acc1[rb][ctl][reg] + b1v[ctl];
                    acc1[rb][ctl][reg] = gelu_exact((x - mean) * rs * g1v[ctl] + be1v[ctl]);
                }
            }
    }

#pragma unroll
    for (int rb = 0; rb < 2; ++rb)
#pragma unroll
        for (int ctl = 0; ctl < 4; ++ctl) {
            unsigned w0, w1, w2, w3;
            pkpair(acc1[rb][ctl][0], acc1[rb][ctl][1], w0, w1);
            pkpair(acc1[rb][ctl][2], acc1[rb][ctl][3], w2, w3);
            int r0 = rb * 16 + lg * 4;
            int kc = w * 64 + ctl * 16 + li;
            hpk[r0 + 0][kc] = w0; hpk[r0 + 1][kc] = w1;
            hpk[r0 + 2][kc] = w2; hpk[r0 + 3][kc] = w3;
        }
    __syncthreads();

    f32x4 acc2[2][4];
#pragma unroll
    for (int rb = 0; rb < 2; ++rb)
#pragma unroll
        for (int ctl = 0; ctl < 4; ++ctl) acc2[rb][ctl] = (f32x4){0.f, 0.f, 0.f, 0.f};
#pragma unroll
    for (int q = 0; q < 8; ++q) {
        s16x8 Bh[4], Bl[4];
#pragma unroll
        for (int ctl = 0; ctl < 4; ++ctl)
            loadB(pk2, (ws4 + ctl) * 8 + q, l, Bh[ctl], Bl[ctl]);
#pragma unroll
        for (int rb = 0; rb < 2; ++rb) {
            const unsigned int* hp = &hpk[rb * 16 + li][q * 32 + lg * 8];
            int4 xa = *(const int4*)hp;
            int4 xb = *(const int4*)(hp + 4);
            unsigned x[8] = {(unsigned)xa.x, (unsigned)xa.y, (unsigned)xa.z, (unsigned)xa.w,
                             (unsigned)xb.x, (unsigned)xb.y, (unsigned)xb.z, (unsigned)xb.w};
            s16x8 Ah2, Al2;
            unpackHL(x, Ah2, Al2);
#pragma unroll
            for (int ctl = 0; ctl < 4; ++ctl) {
                acc2[rb][ctl] = __builtin_amdgcn_mfma_f32_16x16x32_bf16(Ah2, Bh[ctl], acc2[rb][ctl], 0, 0, 0);
                acc2[rb][ctl] = __builtin_amdgcn_mfma_f32_16x16x32_bf16(Ah2, Bl[ctl], acc2[rb][ctl], 0, 0, 0);
                acc2[rb][ctl] = __builtin_amdgcn_mfma_f32_16x16x32_bf16(Al2, Bh[ctl], acc2[rb][ctl], 0, 0, 0);
            }
        }
    }

    float b2v[4], g2v[4], be2v[4];
#pragma unroll
    for (int ctl = 0; ctl < 4; ++ctl) {
        int col = w * 64 + ctl * 16 + li;
        b2v[ctl] = b2[col]; g2v[ctl] = g2[col]; be2v[ctl] = be2[col];
    }
#pragma unroll
    for (int rb = 0; rb < 2; ++rb)
#pragma unroll
        for (int reg = 0; reg < 4; ++reg) {
            float s = 0.f, ss = 0.f;
#pragma unroll
            for (int ctl = 0; ctl < 4; ++ctl) {
                float x = acc2[rb][ctl][reg] + b2v[ctl];
                s += x; ss = fmaf(x, x, ss);
            }
            row_sum16x2(s, ss);
            if (li == 0) {
                lnred[w][rb * 16 + lg * 4 + reg][0] = s;
                lnred[w][rb * 16 + lg * 4 + reg][1] = ss;
            }
        }
    __syncthreads();
#pragma unroll
    for (int rb = 0; rb < 2; ++rb)
#pragma unroll
        for (int reg = 0; reg < 4; ++reg) {
            int row = rb * 16 + lg * 4 + reg;
            float s = lnred[0][row][0] + lnred[1][row][0] + lnred[2][row][0] + lnred[3][row][0];
            float ss = lnred[0][row][1] + lnred[1][row][1] + lnred[2][row][1] + lnred[3][row][1];
            float mean = s * (1.0f / 256.0f);
            float var = ss * (1.0f / 256.0f) - mean * mean;
            float rs = rsqrtf(var + 1e-5f);
#pragma unroll
            for (int ctl = 0; ctl < 4; ++ctl) {
                float x = acc2[rb][ctl][reg] + b2v[ctl];
                float v = (x - mean) * rs * g2v[ctl] + be2v[ctl];
                out[(size_t)(rowbase + row) * TOK + w * 64 + ctl * 16 + li] = v;
            }
        }
}

extern "C" void kernel_launch(void* const* d_in, const int* in_sizes, int n_in,
                              void* d_out, int out_size, void* d_ws, size_t ws_size,
                              hipStream_t stream) {
    const float* xyz  = (const float*)d_in[0];
    const float* pf   = (const float*)d_in[1];
    const float* sW1  = (const float*)d_in[2];
    const float* sb1  = (const float*)d_in[3];
    const float* sg1  = (const float*)d_in[4];
    const float* sbe1 = (const float*)d_in[5];
    const float* sW2  = (const float*)d_in[6];
    const float* sb2  = (const float*)d_in[7];
    const float* sg2  = (const float*)d_in[8];
    const float* sbe2 = (const float*)d_in[9];
    const float* tW1  = (const float*)d_in[10];
    const float* tb1  = (const float*)d_in[11];
    const float* tg1  = (const float*)d_in[12];
    const float* tbe1 = (const float*)d_in[13];
    const float* tW2  = (const float*)d_in[14];
    const float* tb2  = (const float*)d_in[15];
    const float* tg2  = (const float*)d_in[16];
    const float* tbe2 = (const float*)d_in[17];

    float* out_tok = (float*)d_out;
    float* out_pc  = out_tok + (size_t)BATCH * NCTR * TOK;

    char* ws = (char*)d_ws;
    int* center_idx = (int*)ws;   ws += (size_t)BATCH * NCTR * 4;
    float* pc_ws    = (float*)ws; ws += (size_t)BATCH * NCTR * 3 * 4;
    int* nbr0       = (int*)ws;   ws += (size_t)BATCH * NCTR * 16 * 4;
    int* nbr1       = (int*)ws;   ws += (size_t)BATCH * NCTR * 32 * 4;
    int* nbr2       = (int*)ws;   ws += (size_t)BATCH * NCTR * 64 * 4;
    float* sf0      = (float*)ws; ws += (size_t)BATCH * NCTR * TOK * 4;
    float* sf1      = (float*)ws; ws += (size_t)BATCH * NCTR * TOK * 4;
    float* sf2p     = (float*)ws; ws += (size_t)BATCH * NCTR * 2 * TOK * 4;  // K=64 partials
    const size_t PK1_S  = 16 * 5 * 64 * 16;    // ushorts per scale (sW1)
    const size_t PK2_S  = 16 * 8 * 64 * 16;    // ushorts per scale (sW2)
    const size_t PKT1_S = 16 * 31 * 64 * 16;   // ushorts (tW1)
    const size_t PKT2_S = 16 * 8 * 64 * 16;    // ushorts (tW2)
    unsigned short* pkW1 = (unsigned short*)ws; ws += 3 * PK1_S * 2;
    unsigned short* pkW2 = (unsigned short*)ws; ws += 3 * PK2_S * 2;
    unsigned short* pkT1 = (unsigned short*)ws; ws += PKT1_S * 2;
    unsigned short* pkT2 = (unsigned short*)ws; ws += PKT2_S * 2;

    {
        dim3 gp1((16 * 5 * 64 + 255) / 256, 3);
        pack_w<<<gp1, 256, 0, stream>>>(sW1, pkW1, D_IN, 5);
        dim3 gp2((16 * 8 * 64 + 255) / 256, 3);
        pack_w<<<gp2, 256, 0, stream>>>(sW2, pkW2, TOK, 8);
        dim3 gpt1((16 * 31 * 64 + 255) / 256, 1);
        pack_w<<<gpt1, 256, 0, stream>>>(tW1, pkT1, D_TOK, 31);
        dim3 gpt2((16 * 8 * 64 + 255) / 256, 1);
        pack_w<<<gpt2, 256, 0, stream>>>(tW2, pkT2, TOK, 8);
    }

    fps_kernel<<<BATCH, 256, 0, stream>>>(xyz, center_idx, pc_ws, out_pc);

    ballq_kernel<16><<<BATCH * NCTR / 4, 256, 0, stream>>>(xyz, pc_ws, nbr0, (float)(0.1 * 0.1));
    ballq_kernel<32><<<BATCH * NCTR / 4, 256, 0, stream>>>(xyz, pc_ws, nbr1, (float)(0.2 * 0.2));
    ballq_kernel<64><<<BATCH * NCTR / 4, 256, 0, stream>>>(xyz, pc_ws, nbr2, (float)(0.4 * 0.4));

    // 32 rows per block
    scale_mfma<16><<<(BATCH * NCTR * 16) / 32, 256, 0, stream>>>(
        xyz, pf, pkW1 + 0 * PK1_S, sb1 + 0 * TOK, sg1 + 0 * TOK, sbe1 + 0 * TOK,
        pkW2 + 0 * PK2_S, sb2 + 0 * TOK, sg2 + 0 * TOK, sbe2 + 0 * TOK,
        nbr0, pc_ws, sf0);
    scale_mfma<32><<<(BATCH * NCTR * 32) / 32, 256, 0, stream>>>(
        xyz, pf, pkW1 + 1 * PK1_S, sb1 + 1 * TOK, sg1 + 1 * TOK, sbe1 + 1 * TOK,
        pkW2 + 1 * PK2_S, sb2 + 1 * TOK, sg2 + 1 * TOK, sbe2 + 1 * TOK,
        nbr1, pc_ws, sf1);
    scale_mfma<64><<<(BATCH * NCTR * 64) / 32, 256, 0, stream>>>(
        xyz, pf, pkW1 + 2 * PK1_S, sb1 + 2 * TOK, sg1 + 2 * TOK, sbe1 + 2 * TOK,
        pkW2 + 2 * PK2_S, sb2 + 2 * TOK, sg2 + 2 * TOK, sbe2 + 2 * TOK,
        nbr2, pc_ws, sf2p);

    token_mfma<<<(BATCH * NCTR) / 32, 256, 0, stream>>>(
        pf, center_idx, pc_ws, sf0, sf1, sf2p,
        pkT1, tb1, tg1, tbe1, pkT2, tb2, tg2, tbe2, out_tok);
}

// Round 14
// 1321.502 us; speedup vs baseline: 1.3061x; 1.0393x over previous
//
#include <hip/hip_runtime.h>
#include <math.h>

#define BATCH 16
#define NPTS  4096
#define NCTR  512
#define STEM  128
#define TOK   256
#define D_IN  155   // 128 + 3 + 24
#define D_TOK 992   // 128 + 3*256 + 96

typedef short s16x8 __attribute__((ext_vector_type(8)));
typedef float f32x4 __attribute__((ext_vector_type(4)));

// 10000^(-i/15), i=0..15 (token-PE frequencies)
static constexpr float FR15c[16] = {
    1.0f, 0.5411695265464638f, 0.2928644487857941f, 0.15848931670188904f,
    0.08576958626508713f, 0.04641588851809502f, 0.02511886507272720f, 0.01359356392547488f,
    0.007356422487646341f, 0.003981071710586548f, 0.002154434798285365f, 0.001165914465673268f,
    0.0006309573450125754f, 0.0003414548910222948f, 0.0001847849769866168f, 0.0001f};

__device__ __forceinline__ unsigned short f2bf(float f) {
    unsigned u = __float_as_uint(f);
    u += 0x7FFF + ((u >> 16) & 1);
    return (unsigned short)(u >> 16);
}
__device__ __forceinline__ float bf2f(unsigned short b) {
    return __uint_as_float(((unsigned)b) << 16);
}

// split 8 f32 -> hi/lo bf16 fragments via v_cvt_pk_bf16_f32 (RNE)
__device__ __forceinline__ void bsplit8(const float* v, s16x8& hi, s16x8& lo) {
    union { s16x8 s; unsigned w[4]; } H, L;
#pragma unroll
    for (int p = 0; p < 4; ++p) {
        unsigned hp, lp;
        asm("v_cvt_pk_bf16_f32 %0, %1, %2" : "=v"(hp) : "v"(v[2 * p]), "v"(v[2 * p + 1]));
        float r0 = v[2 * p]     - __uint_as_float(hp << 16);
        float r1 = v[2 * p + 1] - __uint_as_float(hp & 0xffff0000u);
        asm("v_cvt_pk_bf16_f32 %0, %1, %2" : "=v"(lp) : "v"(r0), "v"(r1));
        H.w[p] = hp; L.w[p] = lp;
    }
    hi = H.s; lo = L.s;
}

// pack two f32 into two (hi16|lo16) u32 words
__device__ __forceinline__ void pkpair(float v0, float v1, unsigned& w0, unsigned& w1) {
    unsigned hp, lp;
    asm("v_cvt_pk_bf16_f32 %0, %1, %2" : "=v"(hp) : "v"(v0), "v"(v1));
    float r0 = v0 - __uint_as_float(hp << 16);
    float r1 = v1 - __uint_as_float(hp & 0xffff0000u);
    asm("v_cvt_pk_bf16_f32 %0, %1, %2" : "=v"(lp) : "v"(r0), "v"(r1));
    w0 = (hp << 16) | (lp & 0xffffu);
    w1 = (hp & 0xffff0000u) | (lp >> 16);
}

// B-fragment direct load: global (L2-hot) -> VGPR, 16B hi + 16B lo per lane
__device__ __forceinline__ void loadB(const unsigned short* __restrict__ pk,
                                      int frag, int l, s16x8& bh, s16x8& bl) {
    const unsigned short* p = pk + (size_t)frag * 1024 + (size_t)l * 8;
    bh = *(const s16x8*)p;
    bl = *(const s16x8*)(p + 512);
}

// fast exact-GELU: A&S 7.1.26 erf (|abs err| < 2e-7)
__device__ __forceinline__ float gelu_exact(float x) {
    float z = x * 0.70710678118654752f;
    float a = fabsf(z);
    float t = __builtin_amdgcn_rcpf(fmaf(0.3275911f, a, 1.0f));
    float p = fmaf(1.061405429f, t, -1.453152027f);
    p = fmaf(p, t, 1.421413741f);
    p = fmaf(p, t, -0.284496736f);
    p = fmaf(p, t, 0.254829592f);
    p = p * t;
    float e = __expf(-z * z);
    float y = fmaf(-p, e, 1.0f);
    y = (z < 0.0f) ? -y : y;
    return 0.5f * x * (1.0f + y);
}

// exact, non-contracted squared distance to match numpy f32 rounding
__device__ __forceinline__ float sq3(float ax, float ay, float az,
                                     float bx, float by, float bz) {
    float dx = __fsub_rn(ax, bx);
    float dy = __fsub_rn(ay, by);
    float dz = __fsub_rn(az, bz);
    float d = __fmul_rn(dx, dx);
    d = __fadd_rn(d, __fmul_rn(dy, dy));
    d = __fadd_rn(d, __fmul_rn(dz, dz));
    return d;
}

// argmax-combine one DPP row_ror step (total-order max: rotation-valid)
template <int CTRL>
__device__ __forceinline__ void dpp_amax(float& bv, int& bi) {
    int vv = __builtin_amdgcn_update_dpp(__float_as_int(bv), __float_as_int(bv),
                                         CTRL, 0xF, 0xF, false);
    int oi = __builtin_amdgcn_update_dpp(bi, bi, CTRL, 0xF, 0xF, false);
    float ov = __int_as_float(vv);
    if (ov > bv || (ov == bv && oi < bi)) { bv = ov; bi = oi; }
}
__device__ __forceinline__ void row_amax16(float& bv, int& bi) {
    dpp_amax<0x128>(bv, bi);   // row_ror:8
    dpp_amax<0x124>(bv, bi);   // row_ror:4
    dpp_amax<0x122>(bv, bi);   // row_ror:2
    dpp_amax<0x121>(bv, bi);   // row_ror:1
}

// sum-reduce over the 16-lane row via DPP row_ror (register-lane, no LDS pipe)
template <int CTRL>
__device__ __forceinline__ float dpp_fadd(float x) {
    int r = __builtin_amdgcn_update_dpp(0, __float_as_int(x), CTRL, 0xF, 0xF, true);
    return x + __int_as_float(r);
}
__device__ __forceinline__ void row_sum16x2(float& s, float& ss) {
    s = dpp_fadd<0x128>(s);  ss = dpp_fadd<0x128>(ss);
    s = dpp_fadd<0x124>(s);  ss = dpp_fadd<0x124>(ss);
    s = dpp_fadd<0x122>(s);  ss = dpp_fadd<0x122>(ss);
    s = dpp_fadd<0x121>(s);  ss = dpp_fadd<0x121>(ss);
}

// ---------------- FPS: 256 threads, DPP row-reduce, 1 barrier/step ---------
__global__ __launch_bounds__(256) void fps_kernel(const float* __restrict__ xyz,
                                                  int* __restrict__ center_idx,
                                                  float* __restrict__ pc_ws,
                                                  float* __restrict__ pc_out) {
    int b = blockIdx.x;
    int t = threadIdx.x;
    const int w = t >> 6, lane = t & 63;
    const float* X = xyz + (size_t)b * NPTS * 3;
    __shared__ __align__(16) float sxyz[NPTS * 3];  // 48 KB
    __shared__ float swv[2][16];
    __shared__ int   swi[2][16];
    __shared__ int   hist[NCTR];                    // 2 KB
    {
        const float4* src = (const float4*)X;
        float4* dst = (float4*)sxyz;
        for (int i = t; i < NPTS * 3 / 4; i += 256) dst[i] = src[i];
    }
    __syncthreads();
    float px[16], py[16], pz[16], dist[16];
#pragma unroll
    for (int j = 0; j < 16; ++j) {
        int i = t + 256 * j;
        px[j] = sxyz[i * 3 + 0];
        py[j] = sxyz[i * 3 + 1];
        pz[j] = sxyz[i * 3 + 2];
        dist[j] = 1e10f;
    }
    int far = 0;
    for (int s = 0; s < NCTR; ++s) {
        if (t == 0) hist[s] = far;
        float cx = sxyz[far * 3 + 0];
        float cy = sxyz[far * 3 + 1];
        float cz = sxyz[far * 3 + 2];
        float bv = -1.0f;
        int bi = 0;
#pragma unroll
        for (int j = 0; j < 16; ++j) {
            float d = sq3(px[j], py[j], pz[j], cx, cy, cz);
            float nd = fminf(dist[j], d);
            dist[j] = nd;
            if (nd > bv) { bv = nd; bi = t + 256 * j; }  // strict >: earliest idx
        }
        row_amax16(bv, bi);
        const int p = s & 1;
        if ((lane & 15) == 0) {
            int r = w * 4 + (lane >> 4);
            swv[p][r] = bv; swi[p][r] = bi;
        }
        __syncthreads();
        bv = swv[p][lane & 15];
        bi = swi[p][lane & 15];
        row_amax16(bv, bi);
        far = bi;
    }
    __syncthreads();
    for (int s = t; s < NCTR; s += 256) {
        int idx = hist[s];
        center_idx[b * NCTR + s] = idx;
        float cx = sxyz[idx * 3], cy = sxyz[idx * 3 + 1], cz = sxyz[idx * 3 + 2];
        size_t po = (size_t)(b * NCTR + s) * 3;
        pc_ws[po] = cx; pc_ws[po + 1] = cy; pc_ws[po + 2] = cz;
        pc_out[po] = cx; pc_out[po + 1] = cy; pc_out[po + 2] = cz;
    }
}

// ---------------- Ball query (unchanged) ----------------------------------
template <int K>
__global__ __launch_bounds__(256) void ballq_kernel(const float* __restrict__ xyz,
                                                    const float* __restrict__ pc,
                                                    int* __restrict__ nbr,
                                                    float rr) {
    int cid = blockIdx.x * 4 + (threadIdx.x >> 6);
    int lane = threadIdx.x & 63;
    int b = cid >> 9;
    const float* X = xyz + (size_t)b * NPTS * 3;
    float cx = pc[(size_t)cid * 3 + 0];
    float cy = pc[(size_t)cid * 3 + 1];
    float cz = pc[(size_t)cid * 3 + 2];
    int cnt = 0, first = 0;
    bool have_first = false;
    long long base = (long long)cid * K;
    for (int it = 0; it < NPTS / 64; ++it) {
        int i = it * 64 + lane;
        float d = sq3(cx, cy, cz, X[i * 3], X[i * 3 + 1], X[i * 3 + 2]);
        bool ok = d <= rr;
        unsigned long long mask = __ballot(ok);
        if (!have_first && mask) {
            first = it * 64 + (int)__builtin_ctzll(mask);
            have_first = true;
        }
        int pos = cnt + (int)__popcll(mask & ((1ull << lane) - 1ull));
        if (ok && pos < K) nbr[base + pos] = i;
        cnt += (int)__popcll(mask);
        if (cnt >= K) break;
    }
    int fill = cnt < K ? cnt : K;
    for (int j = fill + lane; j < K; j += 64) nbr[base + j] = first;
}

// ---------------- Weight pack: hi-plane/lo-plane bf16 MFMA B-frags --------
__global__ __launch_bounds__(256) void pack_w(const float* __restrict__ Wbase,
                                              unsigned short* __restrict__ out,
                                              int Kdim, int KS) {
    int s = blockIdx.y;
    const float* W = Wbase + (size_t)s * Kdim * TOK;
    unsigned short* o = out + (size_t)s * 16 * KS * 64 * 16;
    int tid = blockIdx.x * 256 + threadIdx.x;
    if (tid >= 16 * KS * 64) return;
    int lane = tid & 63;
    int frag = tid >> 6;
    int ks = frag % KS;
    int ct = frag / KS;
    int col = ct * 16 + (lane & 15);
    int k0 = ks * 32 + (lane >> 4) * 8;
    unsigned short* hi = o + (size_t)frag * 1024 + lane * 8;
    unsigned short* lo = hi + 512;
#pragma unroll
    for (int j = 0; j < 8; ++j) {
        int k = k0 + j;
        float v = (k < Kdim) ? W[(size_t)k * TOK + col] : 0.0f;
        unsigned short h = f2bf(v);
        hi[j] = h;
        lo[j] = f2bf(v - bf2f(h));
    }
}

// unpack 8 hi|lo u32 words -> HI-plane fragment only via v_perm_b32
__device__ __forceinline__ void unpackH(const unsigned* x, s16x8& Ah) {
    union { s16x8 s; unsigned w[4]; } H;
#pragma unroll
    for (int p = 0; p < 4; ++p)
        H.w[p] = __builtin_amdgcn_perm(x[2 * p + 1], x[2 * p], 0x07060302u);
    Ah = H.s;
}

// ---------------- Per-scale grouped MLP via MFMA ---------------------------
// 32-row blocks, ONE-PASS skeleton (round-12 passing structure, unchanged).
// MLP1: bf16x3. MLP2: A = h hi-plane only (post-LN/GELU unit-scale; dropped
// low-plane correction ~0.2-0.4% relative, renormalized by LN2) x B hi/lo
// = 2 MFMA (was 3). hpk layout/park identical to round 12.
// K=64 centers span two blocks: PARTIAL max rows to sf2p; token_mfma combines.
template <int K>
__global__ __launch_bounds__(256, 2) void scale_mfma(
    const float* __restrict__ xyz, const float* __restrict__ pf,
    const unsigned short* __restrict__ pk1, const float* __restrict__ b1,
    const float* __restrict__ g1, const float* __restrict__ be1,
    const unsigned short* __restrict__ pk2, const float* __restrict__ b2,
    const float* __restrict__ g2, const float* __restrict__ be2,
    const int* __restrict__ nbr, const float* __restrict__ pc,
    float* __restrict__ outf) {
    __shared__ unsigned int hpk[32][260];   // 33 KB packed-bf16 h (32 rows)
    __shared__ float lnred[4][32][2];       // 1 KB
    const int w = threadIdx.x >> 6, l = threadIdx.x & 63;
    const int lg = l >> 4, li = l & 15;
    const int ws4 = 4 * w;

    int nb[2];
    float relx[2], rely[2], relz[2];
#pragma unroll
    for (int rb = 0; rb < 2; ++rb) {
        int row_g = blockIdx.x * 32 + rb * 16 + li;
        int c = (blockIdx.x * 32 + rb * 16) / K;   // li never crosses a center
        int b = c >> 9;
        int n = nbr[row_g];
        nb[rb] = b * NPTS + n;
        const float* X = xyz + (size_t)nb[rb] * 3;
        const float* C = pc + (size_t)c * 3;
        relx[rb] = __fsub_rn(X[0], C[0]);
        rely[rb] = __fsub_rn(X[1], C[1]);
        relz[rb] = __fsub_rn(X[2], C[2]);
    }

    // ---------------- MLP1: [32 x 160] @ [160 x 64-slice] (bf16x3) --------
    f32x4 acc1[2][4];
#pragma unroll
    for (int rb = 0; rb < 2; ++rb)
#pragma unroll
        for (int ctl = 0; ctl < 4; ++ctl) acc1[rb][ctl] = (f32x4){0.f, 0.f, 0.f, 0.f};

#pragma unroll
    for (int ks = 0; ks < 5; ++ks) {
        s16x8 Bh[4], Bl[4];
#pragma unroll
        for (int ctl = 0; ctl < 4; ++ctl)
            loadB(pk1, (ws4 + ctl) * 5 + ks, l, Bh[ctl], Bl[ctl]);
        s16x8 Ah[2], Al[2];
#pragma unroll
        for (int rb = 0; rb < 2; ++rb) {
            float v[8];
            if (ks < 4) {
                const float* src = pf + (size_t)nb[rb] * STEM + ks * 32 + lg * 8;
                float4 f0 = *(const float4*)src;
                float4 f1 = *(const float4*)(src + 4);
                v[0] = f0.x; v[1] = f0.y; v[2] = f0.z; v[3] = f0.w;
                v[4] = f1.x; v[5] = f1.y; v[6] = f1.z; v[7] = f1.w;
            } else {
#pragma unroll
                for (int j = 0; j < 8; ++j) {
                    int ch = lg * 8 + j;
                    float val = 0.0f;
                    if (ch < 3) {
                        val = (ch == 0) ? relx[rb] : ((ch == 1) ? rely[rb] : relz[rb]);
                    } else if (ch < 27) {
                        int rem = ch - 3;
                        int axis = rem >> 3, r8 = rem & 7;
                        int fi = (r8 < 4) ? r8 : r8 - 4;
                        float fr = (fi == 0) ? 1.0f
                                  : (fi == 1) ? 0.046415888336127795f
                                  : (fi == 2) ? 0.0021544346900318843f : 1e-4f;
                        float rl = (axis == 0) ? relx[rb] : ((axis == 1) ? rely[rb] : relz[rb]);
                        float ang = rl * fr;
                        val = (r8 < 4) ? __sinf(ang) : __cosf(ang);
                    }
                    v[j] = val;
                }
            }
            bsplit8(v, Ah[rb], Al[rb]);
        }
#pragma unroll
        for (int ctl = 0; ctl < 4; ++ctl)
#pragma unroll
            for (int rb = 0; rb < 2; ++rb) {
                acc1[rb][ctl] = __builtin_amdgcn_mfma_f32_16x16x32_bf16(Ah[rb], Bh[ctl], acc1[rb][ctl], 0, 0, 0);
                acc1[rb][ctl] = __builtin_amdgcn_mfma_f32_16x16x32_bf16(Ah[rb], Bl[ctl], acc1[rb][ctl], 0, 0, 0);
                acc1[rb][ctl] = __builtin_amdgcn_mfma_f32_16x16x32_bf16(Al[rb], Bh[ctl], acc1[rb][ctl], 0, 0, 0);
            }
    }

    // ---------------- bias + LN1 (DPP row-sum + cross-wave) + GELU ---------
    {
        float b1v[4], g1v[4], be1v[4];
#pragma unroll
        for (int ctl = 0; ctl < 4; ++ctl) {
            int col = w * 64 + ctl * 16 + li;
            b1v[ctl] = b1[col]; g1v[ctl] = g1[col]; be1v[ctl] = be1[col];
        }
#pragma unroll
        for (int rb = 0; rb < 2; ++rb)
#pragma unroll
            for (int reg = 0; reg < 4; ++reg) {
                float s = 0.f, ss = 0.f;
#pragma unroll
                for (int ctl = 0; ctl < 4; ++ctl) {
                    float x = acc1[rb][ctl][reg] + b1v[ctl];
                    s += x; ss = fmaf(x, x, ss);
                }
                row_sum16x2(s, ss);
                if (li == 0) {
                    lnred[w][rb * 16 + lg * 4 + reg][0] = s;
                    lnred[w][rb * 16 + lg * 4 + reg][1] = ss;
                }
            }
        __syncthreads();  // B1
#pragma unroll
        for (int rb = 0; rb < 2; ++rb)
#pragma unroll
            for (int reg = 0; reg < 4; ++reg) {
                int row = rb * 16 + lg * 4 + reg;
                float s = lnred[0][row][0] + lnred[1][row][0] + lnred[2][row][0] + lnred[3][row][0];
                float ss = lnred[0][row][1] + lnred[1][row][1] + lnred[2][row][1] + lnred[3][row][1];
                float mean = s * (1.0f / 256.0f);
                float var = ss * (1.0f / 256.0f) - mean * mean;
                float rs = rsqrtf(var + 1e-5f);
#pragma unroll
                for (int ctl = 0; ctl < 4; ++ctl) {
                    float x = acc1[rb][ctl][reg] + b1v[ctl];
                    acc1[rb][ctl][reg] = gelu_exact((x - mean) * rs * g1v[ctl] + be1v[ctl]);
                }
            }
    }

    // ---------------- park FULL h (packed hi|lo u32); acc1 dies here -------
#pragma unroll
    for (int rb = 0; rb < 2; ++rb)
#pragma unroll
        for (int ctl = 0; ctl < 4; ++ctl) {
            unsigned w0, w1, w2, w3;
            pkpair(acc1[rb][ctl][0], acc1[rb][ctl][1], w0, w1);
            pkpair(acc1[rb][ctl][2], acc1[rb][ctl][3], w2, w3);
            int r0 = rb * 16 + lg * 4;
            int kc = w * 64 + ctl * 16 + li;
            hpk[r0 + 0][kc] = w0; hpk[r0 + 1][kc] = w1;
            hpk[r0 + 2][kc] = w2; hpk[r0 + 3][kc] = w3;
        }
    __syncthreads();  // B2

    // ---------------- MLP2: [32 x 256] @ [256 x 64-slice] (A hi, B x2) -----
    f32x4 acc2[2][4];
#pragma unroll
    for (int rb = 0; rb < 2; ++rb)
#pragma unroll
        for (int ctl = 0; ctl < 4; ++ctl) acc2[rb][ctl] = (f32x4){0.f, 0.f, 0.f, 0.f};

#pragma unroll
    for (int q = 0; q < 8; ++q) {
        s16x8 Bh[4], Bl[4];
#pragma unroll
        for (int ctl = 0; ctl < 4; ++ctl)
            loadB(pk2, (ws4 + ctl) * 8 + q, l, Bh[ctl], Bl[ctl]);
#pragma unroll
        for (int rb = 0; rb < 2; ++rb) {
            const unsigned int* hp = &hpk[rb * 16 + li][q * 32 + lg * 8];
            int4 xa = *(const int4*)hp;
            int4 xb = *(const int4*)(hp + 4);
            unsigned x[8] = {(unsigned)xa.x, (unsigned)xa.y, (unsigned)xa.z, (unsigned)xa.w,
                             (unsigned)xb.x, (unsigned)xb.y, (unsigned)xb.z, (unsigned)xb.w};
            s16x8 Ah2;
            unpackH(x, Ah2);
#pragma unroll
            for (int ctl = 0; ctl < 4; ++ctl) {
                acc2[rb][ctl] = __builtin_amdgcn_mfma_f32_16x16x32_bf16(Ah2, Bh[ctl], acc2[rb][ctl], 0, 0, 0);
                acc2[rb][ctl] = __builtin_amdgcn_mfma_f32_16x16x32_bf16(Ah2, Bl[ctl], acc2[rb][ctl], 0, 0, 0);
            }
        }
    }

    // ---------------- bias + LN2 (DPP row-sum + cross-wave) ----------------
    float b2v[4], g2v[4], be2v[4];
#pragma unroll
    for (int ctl = 0; ctl < 4; ++ctl) {
        int col = w * 64 + ctl * 16 + li;
        b2v[ctl] = b2[col]; g2v[ctl] = g2[col]; be2v[ctl] = be2[col];
    }
#pragma unroll
    for (int rb = 0; rb < 2; ++rb)
#pragma unroll
        for (int reg = 0; reg < 4; ++reg) {
            float s = 0.f, ss = 0.f;
#pragma unroll
            for (int ctl = 0; ctl < 4; ++ctl) {
                float x = acc2[rb][ctl][reg] + b2v[ctl];
                s += x; ss = fmaf(x, x, ss);
            }
            row_sum16x2(s, ss);
            if (li == 0) {
                lnred[w][rb * 16 + lg * 4 + reg][0] = s;
                lnred[w][rb * 16 + lg * 4 + reg][1] = ss;
            }
        }
    __syncthreads();  // B3
#pragma unroll
    for (int rb = 0; rb < 2; ++rb)
#pragma unroll
        for (int reg = 0; reg < 4; ++reg) {
            int row = rb * 16 + lg * 4 + reg;
            float s = lnred[0][row][0] + lnred[1][row][0] + lnred[2][row][0] + lnred[3][row][0];
            float ss = lnred[0][row][1] + lnred[1][row][1] + lnred[2][row][1] + lnred[3][row][1];
            float mean = s * (1.0f / 256.0f);
            float var = ss * (1.0f / 256.0f) - mean * mean;
            float rs = rsqrtf(var + 1e-5f);
#pragma unroll
            for (int ctl = 0; ctl < 4; ++ctl) {
                float x = acc2[rb][ctl][reg] + b2v[ctl];
                acc2[rb][ctl][reg] = (x - mean) * rs * g2v[ctl] + be2v[ctl];
            }
        }

    // ---------------- max-pool / emit --------------------------------------
    if (K == 16) {  // two centers per block
#pragma unroll
        for (int rb = 0; rb < 2; ++rb)
#pragma unroll
            for (int ctl = 0; ctl < 4; ++ctl) {
                float mx = -3.4e38f;
#pragma unroll
                for (int reg = 0; reg < 4; ++reg) mx = fmaxf(mx, acc2[rb][ctl][reg]);
                mx = fmaxf(mx, __shfl_xor(mx, 16, 64));
                mx = fmaxf(mx, __shfl_xor(mx, 32, 64));
                if (lg == 0)
                    outf[(size_t)(blockIdx.x * 2 + rb) * TOK + w * 64 + ctl * 16 + li] = mx;
            }
    } else {  // K==32: one center; K==64: partial row (combined in token_mfma)
#pragma unroll
        for (int ctl = 0; ctl < 4; ++ctl) {
            float mx = -3.4e38f;
#pragma unroll
            for (int rb = 0; rb < 2; ++rb)
#pragma unroll
                for (int reg = 0; reg < 4; ++reg) mx = fmaxf(mx, acc2[rb][ctl][reg]);
            mx = fmaxf(mx, __shfl_xor(mx, 16, 64));
            mx = fmaxf(mx, __shfl_xor(mx, 32, 64));
            if (lg == 0)
                outf[(size_t)blockIdx.x * TOK + w * 64 + ctl * 16 + li] = mx;
        }
    }
}

// ---------------- Token MLP via MFMA, tok_in built on the fly --------------
__global__ __launch_bounds__(256, 2) void token_mfma(
    const float* __restrict__ pf, const int* __restrict__ center_idx,
    const float* __restrict__ pc, const float* __restrict__ sf0,
    const float* __restrict__ sf1, const float* __restrict__ sf2p,
    const unsigned short* __restrict__ pk1, const float* __restrict__ b1,
    const float* __restrict__ g1, const float* __restrict__ be1,
    const unsigned short* __restrict__ pk2, const float* __restrict__ b2,
    const float* __restrict__ g2, const float* __restrict__ be2,
    float* __restrict__ out) {
    __shared__ unsigned int hpk[32][260];
    __shared__ float lnred[4][32][2];
    const int w = threadIdx.x >> 6, l = threadIdx.x & 63;
    const int lg = l >> 4, li = l & 15;
    const int ws4 = 4 * w;
    const int rowbase = blockIdx.x * 32;

    int rowg[2];
    const float* pfc[2];
    float pcx[2], pcy[2], pcz[2];
#pragma unroll
    for (int rb = 0; rb < 2; ++rb) {
        int row = rowbase + rb * 16 + li;
        rowg[rb] = row;
        int b = row >> 9;
        int cidx = center_idx[row];
        pfc[rb] = pf + ((size_t)b * NPTS + cidx) * STEM;
        pcx[rb] = pc[(size_t)row * 3 + 0];
        pcy[rb] = pc[(size_t)row * 3 + 1];
        pcz[rb] = pc[(size_t)row * 3 + 2];
    }

    f32x4 acc1[2][4];
#pragma unroll
    for (int rb = 0; rb < 2; ++rb)
#pragma unroll
        for (int ctl = 0; ctl < 4; ++ctl) acc1[rb][ctl] = (f32x4){0.f, 0.f, 0.f, 0.f};

#pragma unroll 2
    for (int ks = 0; ks < 31; ++ks) {
        s16x8 Bh[4], Bl[4];
#pragma unroll
        for (int ctl = 0; ctl < 4; ++ctl)
            loadB(pk1, (ws4 + ctl) * 31 + ks, l, Bh[ctl], Bl[ctl]);
        s16x8 Ah[2], Al[2];
#pragma unroll
        for (int rb = 0; rb < 2; ++rb) {
            float v[8];
            if (ks < 20) {
                const float* src;
                if (ks < 4)       src = pfc[rb] + ks * 32 + lg * 8;
                else if (ks < 12) src = sf0 + (size_t)rowg[rb] * TOK + (ks - 4) * 32 + lg * 8;
                else              src = sf1 + (size_t)rowg[rb] * TOK + (ks - 12) * 32 + lg * 8;
                float4 f0 = *(const float4*)src;
                float4 f1 = *(const float4*)(src + 4);
                v[0] = f0.x; v[1] = f0.y; v[2] = f0.z; v[3] = f0.w;
                v[4] = f1.x; v[5] = f1.y; v[6] = f1.z; v[7] = f1.w;
            } else if (ks < 28) {
                // sf2 = max of the two K=64 partial rows
                const float* sa = sf2p + ((size_t)rowg[rb] * 2) * TOK + (ks - 20) * 32 + lg * 8;
                const float* sb = sa + TOK;
                float4 a0 = *(const float4*)sa;
                float4 a1 = *(const float4*)(sa + 4);
                float4 b0 = *(const float4*)sb;
                float4 b1 = *(const float4*)(sb + 4);
                v[0] = fmaxf(a0.x, b0.x); v[1] = fmaxf(a0.y, b0.y);
                v[2] = fmaxf(a0.z, b0.z); v[3] = fmaxf(a0.w, b0.w);
                v[4] = fmaxf(a1.x, b1.x); v[5] = fmaxf(a1.y, b1.y);
                v[6] = fmaxf(a1.z, b1.z); v[7] = fmaxf(a1.w, b1.w);
            } else {
                float c = (ks == 28) ? pcx[rb] : ((ks == 29) ? pcy[rb] : pcz[rb]);
#pragma unroll
                for (int j = 0; j < 8; ++j) {
                    float fr = (lg & 1) ? FR15c[8 + j] : FR15c[j];
                    float ang = c * fr;
                    v[j] = (lg < 2) ? __sinf(ang) : __cosf(ang);
                }
            }
            bsplit8(v, Ah[rb], Al[rb]);
        }
#pragma unroll
        for (int ctl = 0; ctl < 4; ++ctl)
#pragma unroll
            for (int rb = 0; rb < 2; ++rb) {
                acc1[rb][ctl] = __builtin_amdgcn_mfma_f32_16x16x32_bf16(Ah[rb], Bh[ctl], acc1[rb][ctl], 0, 0, 0);
                acc1[rb][ctl] = __builtin_amdgcn_mfma_f32_16x16x32_bf16(Ah[rb], Bl[ctl], acc1[rb][ctl], 0, 0, 0);
                acc1[rb][ctl] = __builtin_amdgcn_mfma_f32_16x16x32_bf16(Al[rb], Bh[ctl], acc1[rb][ctl], 0, 0, 0);
            }
    }

    {
        float b1v[4], g1v[4], be1v[4];
#pragma unroll
        for (int ctl = 0; ctl < 4; ++ctl) {
            int col = w * 64 + ctl * 16 + li;
            b1v[ctl] = b1[col]; g1v[ctl] = g1[col]; be1v[ctl] = be1[col];
        }
#pragma unroll
        for (int rb = 0; rb < 2; ++rb)
#pragma unroll
            for (int reg = 0; reg < 4; ++reg) {
                float s = 0.f, ss = 0.f;
#pragma unroll
                for (int ctl = 0; ctl < 4; ++ctl) {
                    float x = acc1[rb][ctl][reg] + b1v[ctl];
                    s += x; ss = fmaf(x, x, ss);
                }
                row_sum16x2(s, ss);
                if (li == 0) {
                    lnred[w][rb * 16 + lg * 4 + reg][0] = s;
                    lnred[w][rb * 16 + lg * 4 + reg][1] = ss;
                }
            }
        __syncthreads();
#pragma unroll
        for (int rb = 0; rb < 2; ++rb)
#pragma unroll
            for (int reg = 0; reg < 4; ++reg) {
                int row = rb * 16 + lg * 4 + reg;
                float s = lnred[0][row][0] + lnred[1][row][0] + lnred[2][row][0] + lnred[3][row][0];
                float ss = lnred[0][row][1] + lnred[1][row][1] + lnred[2][row][1] + lnred[3][row][1];
                float mean = s * (1.0f / 256.0f);
                float var = ss * (1.0f / 256.0f) - mean * mean;
                float rs = rsqrtf(var + 1e-5f);
#pragma unroll
                for (int ctl = 0; ctl < 4; ++ctl) {
                    float x = acc1[rb][ctl][reg] + b1v[ctl];
                    acc1[rb][ctl][reg] = gelu_exact((x - mean) * rs * g1v[ctl] + be1v[ctl]);
                }
            }
    }

#pragma unroll
    for (int rb = 0; rb < 2; ++rb)
#pragma unroll
        for (int ctl = 0; ctl < 4; ++ctl) {
            unsigned w0, w1, w2, w3;
            pkpair(acc1[rb][ctl][0], acc1[rb][ctl][1], w0, w1);
            pkpair(acc1[rb][ctl][2], acc1[rb][ctl][3], w2, w3);
            int r0 = rb * 16 + lg * 4;
            int kc = w * 64 + ctl * 16 + li;
            hpk[r0 + 0][kc] = w0; hpk[r0 + 1][kc] = w1;
            hpk[r0 + 2][kc] = w2; hpk[r0 + 3][kc] = w3;
        }
    __syncthreads();

    f32x4 acc2[2][4];
#pragma unroll
    for (int rb = 0; rb < 2; ++rb)
#pragma unroll
        for (int ctl = 0; ctl < 4; ++ctl) acc2[rb][ctl] = (f32x4){0.f, 0.f, 0.f, 0.f};
#pragma unroll
    for (int q = 0; q < 8; ++q) {
        s16x8 Bh[4], Bl[4];
#pragma unroll
        for (int ctl = 0; ctl < 4; ++ctl)
            loadB(pk2, (ws4 + ctl) * 8 + q, l, Bh[ctl], Bl[ctl]);
#pragma unroll
        for (int rb = 0; rb < 2; ++rb) {
            const unsigned int* hp = &hpk[rb * 16 + li][q * 32 + lg * 8];
            int4 xa = *(const int4*)hp;
            int4 xb = *(const int4*)(hp + 4);
            unsigned x[8] = {(unsigned)xa.x, (unsigned)xa.y, (unsigned)xa.z, (unsigned)xa.w,
                             (unsigned)xb.x, (unsigned)xb.y, (unsigned)xb.z, (unsigned)xb.w};
            s16x8 Ah2;
            unpackH(x, Ah2);
#pragma unroll
            for (int ctl = 0; ctl < 4; ++ctl) {
                acc2[rb][ctl] = __builtin_amdgcn_mfma_f32_16x16x32_bf16(Ah2, Bh[ctl], acc2[rb][ctl], 0, 0, 0);
                acc2[rb][ctl] = __builtin_amdgcn_mfma_f32_16x16x32_bf16(Ah2, Bl[ctl], acc2[rb][ctl], 0, 0, 0);
            }
        }
    }

    float b2v[4], g2v[4], be2v[4];
#pragma unroll
    for (int ctl = 0; ctl < 4; ++ctl) {
        int col = w * 64 + ctl * 16 + li;
        b2v[ctl] = b2[col]; g2v[ctl] = g2[col]; be2v[ctl] = be2[col];
    }
#pragma unroll
    for (int rb = 0; rb < 2; ++rb)
#pragma unroll
        for (int reg = 0; reg < 4; ++reg) {
            float s = 0.f, ss = 0.f;
#pragma unroll
            for (int ctl = 0; ctl < 4; ++ctl) {
                float x = acc2[rb][ctl][reg] + b2v[ctl];
                s += x; ss = fmaf(x, x, ss);
            }
            row_sum16x2(s, ss);
            if (li == 0) {
                lnred[w][rb * 16 + lg * 4 + reg][0] = s;
                lnred[w][rb * 16 + lg * 4 + reg][1] = ss;
            }
        }
    __syncthreads();
#pragma unroll
    for (int rb = 0; rb < 2; ++rb)
#pragma unroll
        for (int reg = 0; reg < 4; ++reg) {
            int row = rb * 16 + lg * 4 + reg;
            float s = lnred[0][row][0] + lnred[1][row][0] + lnred[2][row][0] + lnred[3][row][0];
            float ss = lnred[0][row][1] + lnred[1][row][1] + lnred[2][row][1] + lnred[3][row][1];
            float mean = s * (1.0f / 256.0f);
            float var = ss * (1.0f / 256.0f) - mean * mean;
            float rs = rsqrtf(var + 1e-5f);
#pragma unroll
            for (int ctl = 0; ctl < 4; ++ctl) {
                float x = acc2[rb][ctl][reg] + b2v[ctl];
                float v = (x - mean) * rs * g2v[ctl] + be2v[ctl];
                out[(size_t)(rowbase + row) * TOK + w * 64 + ctl * 16 + li] = v;
            }
        }
}

extern "C" void kernel_launch(void* const* d_in, const int* in_sizes, int n_in,
                              void* d_out, int out_size, void* d_ws, size_t ws_size,
                              hipStream_t stream) {
    const float* xyz  = (const float*)d_in[0];
    const float* pf   = (const float*)d_in[1];
    const float* sW1  = (const float*)d_in[2];
    const float* sb1  = (const float*)d_in[3];
    const float* sg1  = (const float*)d_in[4];
    const float* sbe1 = (const float*)d_in[5];
    const float* sW2  = (const float*)d_in[6];
    const float* sb2  = (const float*)d_in[7];
    const float* sg2  = (const float*)d_in[8];
    const float* sbe2 = (const float*)d_in[9];
    const float* tW1  = (const float*)d_in[10];
    const float* tb1  = (const float*)d_in[11];
    const float* tg1  = (const float*)d_in[12];
    const float* tbe1 = (const float*)d_in[13];
    const float* tW2  = (const float*)d_in[14];
    const float* tb2  = (const float*)d_in[15];
    const float* tg2  = (const float*)d_in[16];
    const float* tbe2 = (const float*)d_in[17];

    float* out_tok = (float*)d_out;
    float* out_pc  = out_tok + (size_t)BATCH * NCTR * TOK;

    char* ws = (char*)d_ws;
    int* center_idx = (int*)ws;   ws += (size_t)BATCH * NCTR * 4;
    float* pc_ws    = (float*)ws; ws += (size_t)BATCH * NCTR * 3 * 4;
    int* nbr0       = (int*)ws;   ws += (size_t)BATCH * NCTR * 16 * 4;
    int* nbr1       = (int*)ws;   ws += (size_t)BATCH * NCTR * 32 * 4;
    int* nbr2       = (int*)ws;   ws += (size_t)BATCH * NCTR * 64 * 4;
    float* sf0      = (float*)ws; ws += (size_t)BATCH * NCTR * TOK * 4;
    float* sf1      = (float*)ws; ws += (size_t)BATCH * NCTR * TOK * 4;
    float* sf2p     = (float*)ws; ws += (size_t)BATCH * NCTR * 2 * TOK * 4;  // K=64 partials
    const size_t PK1_S  = 16 * 5 * 64 * 16;    // ushorts per scale (sW1)
    const size_t PK2_S  = 16 * 8 * 64 * 16;    // ushorts per scale (sW2)
    const size_t PKT1_S = 16 * 31 * 64 * 16;   // ushorts (tW1)
    const size_t PKT2_S = 16 * 8 * 64 * 16;    // ushorts (tW2)
    unsigned short* pkW1 = (unsigned short*)ws; ws += 3 * PK1_S * 2;
    unsigned short* pkW2 = (unsigned short*)ws; ws += 3 * PK2_S * 2;
    unsigned short* pkT1 = (unsigned short*)ws; ws += PKT1_S * 2;
    unsigned short* pkT2 = (unsigned short*)ws; ws += PKT2_S * 2;

    {
        dim3 gp1((16 * 5 * 64 + 255) / 256, 3);
        pack_w<<<gp1, 256, 0, stream>>>(sW1, pkW1, D_IN, 5);
        dim3 gp2((16 * 8 * 64 + 255) / 256, 3);
        pack_w<<<gp2, 256, 0, stream>>>(sW2, pkW2, TOK, 8);
        dim3 gpt1((16 * 31 * 64 + 255) / 256, 1);
        pack_w<<<gpt1, 256, 0, stream>>>(tW1, pkT1, D_TOK, 31);
        dim3 gpt2((16 * 8 * 64 + 255) / 256, 1);
        pack_w<<<gpt2, 256, 0, stream>>>(tW2, pkT2, TOK, 8);
    }

    fps_kernel<<<BATCH, 256, 0, stream>>>(xyz, center_idx, pc_ws, out_pc);

    ballq_kernel<16><<<BATCH * NCTR / 4, 256, 0, stream>>>(xyz, pc_ws, nbr0, (float)(0.1 * 0.1));
    ballq_kernel<32><<<BATCH * NCTR / 4, 256, 0, stream>>>(xyz, pc_ws, nbr1, (float)(0.2 * 0.2));
    ballq_kernel<64><<<BATCH * NCTR / 4, 256, 0, stream>>>(xyz, pc_ws, nbr2, (float)(0.4 * 0.4));

    // 32 rows per block
    scale_mfma<16><<<(BATCH * NCTR * 16) / 32, 256, 0, stream>>>(
        xyz, pf, pkW1 + 0 * PK1_S, sb1 + 0 * TOK, sg1 + 0 * TOK, sbe1 + 0 * TOK,
        pkW2 + 0 * PK2_S, sb2 + 0 * TOK, sg2 + 0 * TOK, sbe2 + 0 * TOK,
        nbr0, pc_ws, sf0);
    scale_mfma<32><<<(BATCH * NCTR * 32) / 32, 256, 0, stream>>>(
        xyz, pf, pkW1 + 1 * PK1_S, sb1 + 1 * TOK, sg1 + 1 * TOK, sbe1 + 1 * TOK,
        pkW2 + 1 * PK2_S, sb2 + 1 * TOK, sg2 + 1 * TOK, sbe2 + 1 * TOK,
        nbr1, pc_ws, sf1);
    scale_mfma<64><<<(BATCH * NCTR * 64) / 32, 256, 0, stream>>>(
        xyz, pf, pkW1 + 2 * PK1_S, sb1 + 2 * TOK, sg1 + 2 * TOK, sbe1 + 2 * TOK,
        pkW2 + 2 * PK2_S, sb2 + 2 * TOK, sg2 + 2 * TOK, sbe2 + 2 * TOK,
        nbr2, pc_ws, sf2p);

    token_mfma<<<(BATCH * NCTR) / 32, 256, 0, stream>>>(
        pf, center_idx, pc_ws, sf0, sf1, sf2p,
        pkT1, tb1, tg1, tbe1, pkT2, tb2, tg2, tbe2, out_tok);
}